// Round 1
// baseline (1174.829 us; speedup 1.0000x reference)
//
#include <hip/hip_runtime.h>

typedef __attribute__((ext_vector_type(8))) __bf16 bf16x8;
typedef __attribute__((ext_vector_type(4))) float floatx4;
typedef __attribute__((ext_vector_type(8))) unsigned short ushort8v;
typedef __attribute__((ext_vector_type(4))) unsigned short ushort4v;

namespace {
constexpr int kNU = 100000, kNI = 100000, kE = 600000;
constexpr int kFU = 96, kFI = 160, kH = 128, kOUT = 64;
constexpr float kEPS = 1e-5f;
constexpr int kM = 32;                 // rows per block in MFMA kernels
constexpr int kNCHUNK = 98;            // ceil(100000 / 1024)
constexpr int kNBLK = kNU / kM;        // 3125 row-blocks per node type
constexpr int kEB = (kE + 255) / 256;  // 2344 edge-blocks
}

__device__ __forceinline__ unsigned short f2b(float f) {  // fp32 -> bf16 RNE
  unsigned u = __builtin_bit_cast(unsigned, f);
  u += 0x7FFFu + ((u >> 16) & 1u);
  return (unsigned short)(u >> 16);
}
__device__ __forceinline__ float b2f(unsigned short h) {
  return __builtin_bit_cast(float, (unsigned)h << 16);
}
// 3-way bf16 split: v = h + m + l, residual <= ~2^-27 |v|
__device__ __forceinline__ void split3(float v, unsigned short& h,
                                       unsigned short& m, unsigned short& l) {
  h = f2b(v);
  const float r1 = v - b2f(h);   // exact
  m = f2b(r1);
  const float r2 = r1 - b2f(m);  // exact
  l = f2b(r2);
}
__device__ __forceinline__ bf16x8 ldb8(const unsigned short* p) {
  return __builtin_bit_cast(bf16x8, *(const ushort8v*)p);
}
__device__ __forceinline__ floatx4 mfma16(bf16x8 a, bf16x8 b, floatx4 c) {
  return __builtin_amdgcn_mfma_f32_16x16x32_bf16(a, b, c, 0, 0, 0);
}

// --- weight convert+transpose+3-split: Wh/Wm/Wl[n][k] = split(W[k][n]) ------
struct WcvtArgs {
  const float* src[10];
  unsigned short* dh[10];
  unsigned short* dm[10];
  unsigned short* dl[10];
  int K[10], N[10];
};
__global__ __launch_bounds__(256) void wcvt(WcvtArgs a) {
  const int m = blockIdx.y;
  const int K = a.K[m], N = a.N[m];
  const int idx = blockIdx.x * 256 + threadIdx.x;
  if (idx < K * N) {
    const int n = idx / K, k = idx - n * K;
    unsigned short h, mm, l;
    split3(a.src[m][(size_t)k * N + n], h, mm, l);
    a.dh[m][idx] = h;
    a.dm[m][idx] = mm;
    a.dl[m][idx] = l;
  }
}

// ---------------- CSR build -------------------------------------------------
__global__ void zero_int(int* __restrict__ p, int n) {
  int i = blockIdx.x * blockDim.x + threadIdx.x;
  const int st = gridDim.x * blockDim.x;
  for (; i < n; i += st) p[i] = 0;
}

// exclusive scan within 1024-chunk; chunk totals to tot[dir*128 + chunk]
__global__ __launch_bounds__(1024) void scanA(const int* __restrict__ cnt_u,
                                              const int* __restrict__ cnt_i,
                                              int* ptr_u, int* ptr_i, int* tot) {
  __shared__ int sh[1024];
  const int dir = blockIdx.y;
  const int* cnt = dir ? cnt_i : cnt_u;
  int* ptr = dir ? ptr_i : ptr_u;
  const int t = threadIdx.x;
  const int i = blockIdx.x * 1024 + t;
  const int v = (i < kNU) ? cnt[i] : 0;
  sh[t] = v;
  __syncthreads();
  for (int o = 1; o < 1024; o <<= 1) {
    const int y = (t >= o) ? sh[t - o] : 0;
    __syncthreads();
    sh[t] += y;
    __syncthreads();
  }
  if (i < kNU) ptr[i] = sh[t] - v;  // exclusive within chunk
  if (t == 1023) tot[dir * 128 + blockIdx.x] = sh[1023];
}

// exclusive scan of the (<=98) chunk totals; one block per direction
__global__ __launch_bounds__(128) void scanB(int* tot) {
  __shared__ int sh[128];
  int* tp = tot + blockIdx.x * 128;
  const int t = threadIdx.x;
  const int v = (t < kNCHUNK) ? tp[t] : 0;
  sh[t] = v;
  __syncthreads();
  for (int o = 1; o < 128; o <<= 1) {
    const int y = (t >= o) ? sh[t - o] : 0;
    __syncthreads();
    sh[t] += y;
    __syncthreads();
  }
  if (t < kNCHUNK) tp[t] = sh[t] - v;  // exclusive
}

__global__ __launch_bounds__(1024) void scanC(int* ptr_u, int* ptr_i,
                                              const int* __restrict__ tot,
                                              int* cur_u, int* cur_i) {
  const int dir = blockIdx.y;
  int* ptr = dir ? ptr_i : ptr_u;
  int* cur = dir ? cur_i : cur_u;
  const int i = blockIdx.x * 1024 + threadIdx.x;
  if (i < kNU) {
    const int v = ptr[i] + tot[dir * 128 + blockIdx.x];
    ptr[i] = v;
    cur[i] = v;
  }
}

// ------- projection body: relu(x @ Wp + b) -> fp32, 3-split bf16 MFMA -------
// Called from heterogeneous kernels under a block-uniform branch.
template <int F>
__device__ __forceinline__ void proj_body(
    const float* __restrict__ x, const unsigned short* __restrict__ Wh,
    const unsigned short* __restrict__ Wm, const unsigned short* __restrict__ Wl,
    const float* __restrict__ bias, float* __restrict__ out, int blk,
    unsigned short* sh) {
  constexpr int AS = F + 8, KC = F / 32;
  unsigned short* Ah = sh;
  unsigned short* Am = sh + kM * AS;
  unsigned short* Al = sh + 2 * kM * AS;
  const int tid = threadIdx.x;
  const size_t row0 = (size_t)blk * kM;
  for (int c = tid; c < kM * (F / 4); c += 256) {
    const int r = c / (F / 4), j = c % (F / 4);
    const float4 v = *(const float4*)&x[(row0 + r) * F + j * 4];
    const float* vv = &v.x;
    ushort4v h4, m4, l4;
#pragma unroll
    for (int u = 0; u < 4; ++u) {
      unsigned short th, tm, tl;
      split3(vv[u], th, tm, tl);
      h4[u] = th; m4[u] = tm; l4[u] = tl;
    }
    *(ushort4v*)&Ah[r * AS + j * 4] = h4;
    *(ushort4v*)&Am[r * AS + j * 4] = m4;
    *(ushort4v*)&Al[r * AS + j * 4] = l4;
  }
  const int lane = tid & 63, w = tid >> 6, q = lane >> 4, ln = lane & 15;
  floatx4 acc[2][2] = {}, accL[2][2] = {};
  __syncthreads();
#pragma unroll
  for (int kc = 0; kc < KC; ++kc) {
    bf16x8 bh[2], bm[2], bl_[2];
#pragma unroll
    for (int t = 0; t < 2; ++t) {
      const int off = (w * 32 + t * 16 + ln) * F + kc * 32 + q * 8;
      bh[t] = ldb8(&Wh[off]);
      bm[t] = ldb8(&Wm[off]);
      bl_[t] = ldb8(&Wl[off]);
    }
#pragma unroll
    for (int mt = 0; mt < 2; ++mt) {
      const int ro = mt * 16 + ln, co = kc * 32 + q * 8;
      const bf16x8 ah = ldb8(&Ah[ro * AS + co]);
      const bf16x8 am = ldb8(&Am[ro * AS + co]);
      const bf16x8 al = ldb8(&Al[ro * AS + co]);
#pragma unroll
      for (int t = 0; t < 2; ++t) {
        acc[mt][t] = mfma16(ah, bh[t], acc[mt][t]);  // full scale
        floatx4 cl = accL[mt][t];                    // low-order (~2^-9)
        cl = mfma16(ah, bm[t], cl);
        cl = mfma16(am, bh[t], cl);
        cl = mfma16(ah, bl_[t], cl);
        cl = mfma16(al, bh[t], cl);
        cl = mfma16(am, bm[t], cl);
        accL[mt][t] = cl;
      }
    }
  }
#pragma unroll
  for (int t = 0; t < 2; ++t) {
    const int col = w * 32 + t * 16 + ln;
    const float bv = bias[col];
#pragma unroll
    for (int mt = 0; mt < 2; ++mt)
#pragma unroll
      for (int r = 0; r < 4; ++r)
        out[(row0 + mt * 16 + q * 4 + r) * kH + col] =
            fmaxf((acc[mt][t][r] + accL[mt][t][r]) + bv, 0.f);
  }
}

// --- heterogeneous kernel 1: edge-histogram blocks || user-projection -------
__global__ __launch_bounds__(256) void hist_proj(
    const int* __restrict__ eui, const int* __restrict__ eiu, int* cnt_i,
    int* cnt_u, const float* __restrict__ x,
    const unsigned short* __restrict__ Wh, const unsigned short* __restrict__ Wm,
    const unsigned short* __restrict__ Wl, const float* __restrict__ bias,
    float* __restrict__ out) {
  __shared__ __align__(16) unsigned short sh[3 * kM * (kFU + 8)];
  if (blockIdx.x < kEB) {  // histogram of edge destinations
    const int e = blockIdx.x * 256 + threadIdx.x;
    if (e < kE) {
      atomicAdd(&cnt_i[eui[kE + e]], 1);  // dst items
      atomicAdd(&cnt_u[eiu[kE + e]], 1);  // dst users
    }
  } else {  // user projection (F=96)
    proj_body<kFU>(x, Wh, Wm, Wl, bias, out, blockIdx.x - kEB, sh);
  }
}

// --- heterogeneous kernel 2: CSR fill blocks || item-projection -------------
// after fill: cur[dst] == ptr[dst] + degree  (used as `end` by the gather)
__global__ __launch_bounds__(256) void fill_proj(
    const int* __restrict__ eui, const int* __restrict__ eiu, int* cur_i,
    int* cur_u, int* __restrict__ col_ui, int* __restrict__ col_iu,
    const float* __restrict__ x, const unsigned short* __restrict__ Wh,
    const unsigned short* __restrict__ Wm, const unsigned short* __restrict__ Wl,
    const float* __restrict__ bias, float* __restrict__ out) {
  __shared__ __align__(16) unsigned short sh[3 * kM * (kFI + 8)];
  if (blockIdx.x < kEB) {  // CSR column fill
    const int e = blockIdx.x * 256 + threadIdx.x;
    if (e < kE) {
      const int p = atomicAdd(&cur_i[eui[kE + e]], 1);
      col_ui[p] = eui[e];
      const int p2 = atomicAdd(&cur_u[eiu[kE + e]], 1);
      col_iu[p2] = eiu[e];
    }
  } else {  // item projection (F=160)
    proj_body<kFI>(x, Wh, Wm, Wl, bias, out, blockIdx.x - kEB, sh);
  }
}

// --- fused gather-mean + SAGE + bias + LN (+ReLU), both directions ----------
// Block b < kNBLK: dir 0 (dst=items). Else dir 1 (dst=users).
// Per block: gather-mean 32 dst rows from gsrc via CSR (fp32, identical sum
// order to the old agg_mean), split3 -> LDS planes 0..2; stage root rows ->
// planes 3..5; then D = A1 @ WL^T + A2 @ WR^T + bl; row LayerNorm [+ReLU].
struct FsArgs {
  const float* gsrc[2];  // gather source feature table
  const float* root[2];  // destination (root) feature table
  const int* ptr[2];
  const int* cur[2];
  const int* col[2];
  const unsigned short *WLh[2], *WLm[2], *WLl[2];
  const unsigned short *WRh[2], *WRm[2], *WRl[2];
  const float *bl[2], *g[2], *b[2];
  float* out[2];
};

template <int NOUT, bool RELU>
__global__ __launch_bounds__(256) void fsage(FsArgs a) {
  constexpr int K = 128, AS = K + 8;
  __shared__ __align__(16) unsigned short Ab[6][kM][AS];  // A1{h,m,l} A2{h,m,l}
  float* Cs = (float*)&Ab[0][0][0];  // reused post-MFMA: [kM][NOUT+1] fp32
  const int tid = threadIdx.x;
  const int dir = (blockIdx.x >= kNBLK) ? 1 : 0;
  const int blk = blockIdx.x - dir * kNBLK;
  const size_t row0 = (size_t)blk * kM;
  const float* __restrict__ gsrc = a.gsrc[dir];
  const float* __restrict__ root = a.root[dir];
  const int* __restrict__ ptr = a.ptr[dir];
  const int* __restrict__ cur = a.cur[dir];
  const int* __restrict__ col = a.col[dir];

  // Phase A: stage root rows (A2) -> planes 3..5 (coalesced float4)
  for (int c = tid; c < kM * (K / 4); c += 256) {
    const int r = c >> 5, j = c & 31;
    const float4 v = *(const float4*)&root[(row0 + r) * K + j * 4];
    const float* vv = &v.x;
    ushort4v h4, m4, l4;
#pragma unroll
    for (int u = 0; u < 4; ++u) {
      unsigned short th, tm, tl;
      split3(vv[u], th, tm, tl);
      h4[u] = th; m4[u] = tm; l4[u] = tl;
    }
    *(ushort4v*)&Ab[3][r][j * 4] = h4;
    *(ushort4v*)&Ab[4][r][j * 4] = m4;
    *(ushort4v*)&Ab[5][r][j * 4] = l4;
  }

  // Phase B: gather-mean (A1) -> planes 0..2. One wave per row, 8 rows/wave.
  const int w = tid >> 6, lane = tid & 63;
  for (int rr = w; rr < kM; rr += 4) {
    const int beg = ptr[row0 + rr], end = cur[row0 + rr];
    float s0 = 0.f, s1 = 0.f;
    for (int e = beg; e < end; ++e) {
      const float2 v = *(const float2*)&gsrc[(size_t)col[e] * K + lane * 2];
      s0 += v.x;
      s1 += v.y;
    }
    const float inv = 1.0f / fmaxf((float)(end - beg), 1.0f);
    s0 *= inv;
    s1 *= inv;
    unsigned short h0, m0, l0, h1, m1, l1;
    split3(s0, h0, m0, l0);
    split3(s1, h1, m1, l1);
    *(unsigned*)&Ab[0][rr][lane * 2] = (unsigned)h0 | ((unsigned)h1 << 16);
    *(unsigned*)&Ab[1][rr][lane * 2] = (unsigned)m0 | ((unsigned)m1 << 16);
    *(unsigned*)&Ab[2][rr][lane * 2] = (unsigned)l0 | ((unsigned)l1 << 16);
  }

  const int q = lane >> 4, ln = lane & 15;
  constexpr int TW = NOUT / 64;  // output tiles per wave (2 for 128, 1 for 64)
  floatx4 acc[2][TW] = {}, accL[2][TW] = {};
  const unsigned short* __restrict__ WLh = a.WLh[dir];
  const unsigned short* __restrict__ WLm = a.WLm[dir];
  const unsigned short* __restrict__ WLl = a.WLl[dir];
  const unsigned short* __restrict__ WRh = a.WRh[dir];
  const unsigned short* __restrict__ WRm = a.WRm[dir];
  const unsigned short* __restrict__ WRl = a.WRl[dir];
  __syncthreads();
#pragma unroll
  for (int kc = 0; kc < 4; ++kc) {
    bf16x8 BL[3][TW], BR[3][TW];
#pragma unroll
    for (int t = 0; t < TW; ++t) {
      const int off = ((w * TW + t) * 16 + ln) * K + kc * 32 + q * 8;
      BL[0][t] = ldb8(&WLh[off]);
      BL[1][t] = ldb8(&WLm[off]);
      BL[2][t] = ldb8(&WLl[off]);
      BR[0][t] = ldb8(&WRh[off]);
      BR[1][t] = ldb8(&WRm[off]);
      BR[2][t] = ldb8(&WRl[off]);
    }
#pragma unroll
    for (int mt = 0; mt < 2; ++mt) {
      const int ro = mt * 16 + ln, co = kc * 32 + q * 8;
      const bf16x8 a1h = ldb8(&Ab[0][ro][co]);
      const bf16x8 a1m = ldb8(&Ab[1][ro][co]);
      const bf16x8 a1l = ldb8(&Ab[2][ro][co]);
      const bf16x8 a2h = ldb8(&Ab[3][ro][co]);
      const bf16x8 a2m = ldb8(&Ab[4][ro][co]);
      const bf16x8 a2l = ldb8(&Ab[5][ro][co]);
#pragma unroll
      for (int t = 0; t < TW; ++t) {
        floatx4 c = acc[mt][t];  // full-scale h*h terms
        c = mfma16(a1h, BL[0][t], c);
        c = mfma16(a2h, BR[0][t], c);
        acc[mt][t] = c;
        floatx4 cl = accL[mt][t];  // low-order terms (~2^-9)
        cl = mfma16(a1h, BL[1][t], cl);
        cl = mfma16(a1m, BL[0][t], cl);
        cl = mfma16(a1h, BL[2][t], cl);
        cl = mfma16(a1l, BL[0][t], cl);
        cl = mfma16(a1m, BL[1][t], cl);
        cl = mfma16(a2h, BR[1][t], cl);
        cl = mfma16(a2m, BR[0][t], cl);
        cl = mfma16(a2h, BR[2][t], cl);
        cl = mfma16(a2l, BR[0][t], cl);
        cl = mfma16(a2m, BR[1][t], cl);
        accL[mt][t] = cl;
      }
    }
  }
  __syncthreads();  // done reading Ab; safe to overwrite with Cs
  const float* __restrict__ blv = a.bl[dir];
#pragma unroll
  for (int t = 0; t < TW; ++t) {
    const int colx = (w * TW + t) * 16 + ln;
    const float bv = blv[colx];
#pragma unroll
    for (int mt = 0; mt < 2; ++mt)
#pragma unroll
      for (int r = 0; r < 4; ++r)
        Cs[(mt * 16 + q * 4 + r) * (NOUT + 1) + colx] =
            (acc[mt][t][r] + accL[mt][t][r]) + bv;
  }
  __syncthreads();
  // Two-pass LayerNorm: 8 threads per row, NOUT/8 cols each
  constexpr int TPR = 8, CPT = NOUT / TPR;
  const int r = tid >> 3, sub = tid & 7;
  const float* __restrict__ gg = a.g[dir];
  const float* __restrict__ bb = a.b[dir];
  float vals[CPT], s = 0.f;
#pragma unroll
  for (int j = 0; j < CPT; ++j) {
    const float v = Cs[r * (NOUT + 1) + sub * CPT + j];
    vals[j] = v;
    s += v;
  }
#pragma unroll
  for (int o = 1; o < TPR; o <<= 1) s += __shfl_xor(s, o, 64);
  const float mean = s * (1.0f / NOUT);
  float s2 = 0.f;
#pragma unroll
  for (int j = 0; j < CPT; ++j) {
    const float d = vals[j] - mean;
    s2 += d * d;
  }
#pragma unroll
  for (int o = 1; o < TPR; o <<= 1) s2 += __shfl_xor(s2, o, 64);
  const float rstd = rsqrtf(s2 * (1.0f / NOUT) + kEPS);
  float* op = a.out[dir] + (row0 + r) * NOUT + sub * CPT;
#pragma unroll
  for (int j = 0; j < CPT; j += 4) {
    float4 o4;
    float* oo = &o4.x;
#pragma unroll
    for (int jj = 0; jj < 4; ++jj) {
      float o = (vals[j + jj] - mean) * rstd * gg[sub * CPT + j + jj] +
                bb[sub * CPT + j + jj];
      if (RELU) o = fmaxf(o, 0.f);
      oo[jj] = o;
    }
    *(float4*)&op[j] = o4;
  }
}

extern "C" void kernel_launch(void* const* d_in, const int* in_sizes, int n_in,
                              void* d_out, int out_size, void* d_ws, size_t ws_size,
                              hipStream_t stream) {
  (void)in_sizes; (void)n_in; (void)out_size; (void)ws_size;
  const float* x_u    = (const float*)d_in[0];
  const float* x_i    = (const float*)d_in[1];
  const int*   e_ui   = (const int*)d_in[2];
  const int*   e_iu   = (const int*)d_in[3];
  const float* Wp_u   = (const float*)d_in[4];
  const float* bp_u   = (const float*)d_in[5];
  const float* Wp_i   = (const float*)d_in[6];
  const float* bp_i   = (const float*)d_in[7];
  const float* Wl0_ui = (const float*)d_in[8];
  const float* bl0_ui = (const float*)d_in[9];
  const float* Wr0_ui = (const float*)d_in[10];
  const float* Wl0_iu = (const float*)d_in[11];
  const float* bl0_iu = (const float*)d_in[12];
  const float* Wr0_iu = (const float*)d_in[13];
  const float* g0_u   = (const float*)d_in[14];
  const float* b0_u   = (const float*)d_in[15];
  const float* g0_i   = (const float*)d_in[16];
  const float* b0_i   = (const float*)d_in[17];
  const float* Wl1_ui = (const float*)d_in[18];
  const float* bl1_ui = (const float*)d_in[19];
  const float* Wr1_ui = (const float*)d_in[20];
  const float* Wl1_iu = (const float*)d_in[21];
  const float* bl1_iu = (const float*)d_in[22];
  const float* Wr1_iu = (const float*)d_in[23];
  const float* g1_u   = (const float*)d_in[24];
  const float* b1_u   = (const float*)d_in[25];
  const float* g1_i   = (const float*)d_in[26];
  const float* b1_i   = (const float*)d_in[27];

  // ---- workspace: 4 fp32 tables (205 MB) + 3-split weights + CSR (~8 MB) --
  float* pf = (float*)d_ws;
  const size_t NH = (size_t)kNU * kH;  // 12.8M
  float* hu0 = pf;           // projected user feats
  float* hi0 = pf + NH;      // projected item feats
  float* hu1 = pf + 2 * NH;  // layer-0 user output
  float* hi1 = pf + 3 * NH;  // layer-0 item output
  unsigned short* wh = (unsigned short*)(pf + 4 * NH);  // 131072 ushorts each
  unsigned short* wm = wh + 131072;
  unsigned short* wl = wm + 131072;
  int* pi = (int*)(wl + 131072);
  int* cnt_u = pi; pi += kNU;
  int* cnt_i = pi; pi += kNU;
  int* ptr_u = pi; pi += kNU;
  int* ptr_i = pi; pi += kNU;
  int* cur_u = pi; pi += kNU;
  int* cur_i = pi; pi += kNU;
  int* tot   = pi; pi += 2 * 128;
  int* col_ui = pi; pi += kE;
  int* col_iu = pi; pi += kE;

  // weight sub-offsets (identical layout in h/m/l sets)
  const int oPu = 0, oPi = 12288, o0Lui = 32768, o0Rui = 49152,
            o0Liu = 65536, o0Riu = 81920, o1Lui = 98304, o1Rui = 106496,
            o1Liu = 114688, o1Riu = 122880;

  float* out_u = (float*)d_out;               // h_u2: [100000][64]
  float* out_i = out_u + (size_t)kNU * kOUT;  // h_i2: [100000][64]

  // ---- weight convert/transpose/3-split ----
  WcvtArgs wa;
  const float* wsrc[10] = {Wp_u, Wp_i, Wl0_ui, Wr0_ui, Wl0_iu, Wr0_iu,
                           Wl1_ui, Wr1_ui, Wl1_iu, Wr1_iu};
  const int woff[10] = {oPu, oPi, o0Lui, o0Rui, o0Liu, o0Riu,
                        o1Lui, o1Rui, o1Liu, o1Riu};
  const int wK[10] = {kFU, kFI, kH, kH, kH, kH, kH, kH, kH, kH};
  const int wN[10] = {kH, kH, kH, kH, kH, kH, kOUT, kOUT, kOUT, kOUT};
  for (int i = 0; i < 10; ++i) {
    wa.src[i] = wsrc[i];
    wa.dh[i] = wh + woff[i];
    wa.dm[i] = wm + woff[i];
    wa.dl[i] = wl + woff[i];
    wa.K[i] = wK[i];
    wa.N[i] = wN[i];
  }
  wcvt<<<dim3(80, 10), 256, 0, stream>>>(wa);

  // ---- CSR build overlapped with projections (heterogeneous grids) ----
  zero_int<<<256, 256, 0, stream>>>(cnt_u, 2 * kNU);  // cnt_u, cnt_i contiguous
  hist_proj<<<kEB + kNBLK, 256, 0, stream>>>(e_ui, e_iu, cnt_i, cnt_u, x_u,
                                             wh + oPu, wm + oPu, wl + oPu,
                                             bp_u, hu0);
  scanA<<<dim3(kNCHUNK, 2), 1024, 0, stream>>>(cnt_u, cnt_i, ptr_u, ptr_i, tot);
  scanB<<<2, 128, 0, stream>>>(tot);
  scanC<<<dim3(kNCHUNK, 2), 1024, 0, stream>>>(ptr_u, ptr_i, tot, cur_u, cur_i);
  fill_proj<<<kEB + kNBLK, 256, 0, stream>>>(e_ui, e_iu, cur_i, cur_u, col_ui,
                                             col_iu, x_i, wh + oPi, wm + oPi,
                                             wl + oPi, bp_i, hi0);

  // ---- layer 0 (both directions fused): h_i1 <- (agg hu0, root hi0),
  //      h_u1 <- (agg hi0, root hu0) ----
  FsArgs a0;
  a0.gsrc[0] = hu0;  a0.root[0] = hi0;
  a0.ptr[0] = ptr_i; a0.cur[0] = cur_i; a0.col[0] = col_ui;
  a0.WLh[0] = wh + o0Lui; a0.WLm[0] = wm + o0Lui; a0.WLl[0] = wl + o0Lui;
  a0.WRh[0] = wh + o0Rui; a0.WRm[0] = wm + o0Rui; a0.WRl[0] = wl + o0Rui;
  a0.bl[0] = bl0_ui; a0.g[0] = g0_i; a0.b[0] = b0_i; a0.out[0] = hi1;
  a0.gsrc[1] = hi0;  a0.root[1] = hu0;
  a0.ptr[1] = ptr_u; a0.cur[1] = cur_u; a0.col[1] = col_iu;
  a0.WLh[1] = wh + o0Liu; a0.WLm[1] = wm + o0Liu; a0.WLl[1] = wl + o0Liu;
  a0.WRh[1] = wh + o0Riu; a0.WRm[1] = wm + o0Riu; a0.WRl[1] = wl + o0Riu;
  a0.bl[1] = bl0_iu; a0.g[1] = g0_u; a0.b[1] = b0_u; a0.out[1] = hu1;
  fsage<kH, true><<<2 * kNBLK, 256, 0, stream>>>(a0);

  // ---- layer 1 (both directions fused): out_i <- (agg hu1, root hi1),
  //      out_u <- (agg hi1, root hu1) ----
  FsArgs a1;
  a1.gsrc[0] = hu1;  a1.root[0] = hi1;
  a1.ptr[0] = ptr_i; a1.cur[0] = cur_i; a1.col[0] = col_ui;
  a1.WLh[0] = wh + o1Lui; a1.WLm[0] = wm + o1Lui; a1.WLl[0] = wl + o1Lui;
  a1.WRh[0] = wh + o1Rui; a1.WRm[0] = wm + o1Rui; a1.WRl[0] = wl + o1Rui;
  a1.bl[0] = bl1_ui; a1.g[0] = g1_i; a1.b[0] = b1_i; a1.out[0] = out_i;
  a1.gsrc[1] = hi1;  a1.root[1] = hu1;
  a1.ptr[1] = ptr_u; a1.cur[1] = cur_u; a1.col[1] = col_iu;
  a1.WLh[1] = wh + o1Liu; a1.WLm[1] = wm + o1Liu; a1.WLl[1] = wl + o1Liu;
  a1.WRh[1] = wh + o1Riu; a1.WRm[1] = wm + o1Riu; a1.WRl[1] = wl + o1Riu;
  a1.bl[1] = bl1_iu; a1.g[1] = g1_u; a1.b[1] = b1_u; a1.out[1] = out_u;
  fsage<kOUT, false><<<2 * kNBLK, 256, 0, stream>>>(a1);
}

// Round 3
// 816.273 us; speedup vs baseline: 1.4393x; 1.4393x over previous
//
#include <hip/hip_runtime.h>

typedef __attribute__((ext_vector_type(8))) __bf16 bf16x8;
typedef __attribute__((ext_vector_type(4))) float floatx4;
typedef __attribute__((ext_vector_type(8))) unsigned short ushort8v;
typedef __attribute__((ext_vector_type(4))) unsigned short ushort4v;

namespace {
constexpr int kNU = 100000, kNI = 100000, kE = 600000;
constexpr int kFU = 96, kFI = 160, kH = 128, kOUT = 64;
constexpr float kEPS = 1e-5f;
constexpr int kM = 32;                 // rows per block in MFMA kernels
constexpr int kNCHUNK = 98;            // ceil(100000 / 1024)
constexpr int kNBLK = kNU / kM;        // 3125 row-blocks per node type
constexpr int kEB = (kE + 255) / 256;  // 2344 edge-blocks
}

__device__ __forceinline__ unsigned short f2b(float f) {  // fp32 -> bf16 RNE
  unsigned u = __builtin_bit_cast(unsigned, f);
  u += 0x7FFFu + ((u >> 16) & 1u);
  return (unsigned short)(u >> 16);
}
__device__ __forceinline__ float b2f(unsigned short h) {
  return __builtin_bit_cast(float, (unsigned)h << 16);
}
// 3-way bf16 split: v = h + m + l, residual <= ~2^-27 |v|
__device__ __forceinline__ void split3(float v, unsigned short& h,
                                       unsigned short& m, unsigned short& l) {
  h = f2b(v);
  const float r1 = v - b2f(h);   // exact
  m = f2b(r1);
  const float r2 = r1 - b2f(m);  // exact
  l = f2b(r2);
}
// 2-way bf16 split: v = h + m, residual <= ~2^-18 |v|
__device__ __forceinline__ void split2(float v, unsigned short& h,
                                       unsigned short& m) {
  h = f2b(v);
  m = f2b(v - b2f(h));
}
__device__ __forceinline__ bf16x8 ldb8(const unsigned short* p) {
  return __builtin_bit_cast(bf16x8, *(const ushort8v*)p);
}
__device__ __forceinline__ floatx4 mfma16(bf16x8 a, bf16x8 b, floatx4 c) {
  return __builtin_amdgcn_mfma_f32_16x16x32_bf16(a, b, c, 0, 0, 0);
}
// Swizzled LDS accessor: plane stride 8 KB, row stride 256 B, XOR bank swizzle
__device__ __forceinline__ unsigned short* ab_ptr(unsigned short* base,
                                                  int plane, int r, int bo) {
  return (unsigned short*)((char*)base + plane * 8192 + r * 256 +
                           (bo ^ ((r & 7) << 4)));
}

// --- weight convert+transpose+3-split: Wh/Wm/Wl[n][k] = split(W[k][n]) ------
struct WcvtArgs {
  const float* src[10];
  unsigned short* dh[10];
  unsigned short* dm[10];
  unsigned short* dl[10];
  int K[10], N[10];
};
__global__ __launch_bounds__(256) void wcvt(WcvtArgs a) {
  const int m = blockIdx.y;
  const int K = a.K[m], N = a.N[m];
  const int idx = blockIdx.x * 256 + threadIdx.x;
  if (idx < K * N) {
    const int n = idx / K, k = idx - n * K;
    unsigned short h, mm, l;
    split3(a.src[m][(size_t)k * N + n], h, mm, l);
    a.dh[m][idx] = h;
    a.dm[m][idx] = mm;
    a.dl[m][idx] = l;
  }
}

// ---------------- CSR build -------------------------------------------------
__global__ void zero_int(int* __restrict__ p, int n) {
  int i = blockIdx.x * blockDim.x + threadIdx.x;
  const int st = gridDim.x * blockDim.x;
  for (; i < n; i += st) p[i] = 0;
}

// exclusive scan within 1024-chunk; chunk totals to tot[dir*128 + chunk]
__global__ __launch_bounds__(1024) void scanA(const int* __restrict__ cnt_u,
                                              const int* __restrict__ cnt_i,
                                              int* ptr_u, int* ptr_i, int* tot) {
  __shared__ int sh[1024];
  const int dir = blockIdx.y;
  const int* cnt = dir ? cnt_i : cnt_u;
  int* ptr = dir ? ptr_i : ptr_u;
  const int t = threadIdx.x;
  const int i = blockIdx.x * 1024 + t;
  const int v = (i < kNU) ? cnt[i] : 0;
  sh[t] = v;
  __syncthreads();
  for (int o = 1; o < 1024; o <<= 1) {
    const int y = (t >= o) ? sh[t - o] : 0;
    __syncthreads();
    sh[t] += y;
    __syncthreads();
  }
  if (i < kNU) ptr[i] = sh[t] - v;  // exclusive within chunk
  if (t == 1023) tot[dir * 128 + blockIdx.x] = sh[1023];
}

// exclusive scan of the (<=98) chunk totals; one block per direction
__global__ __launch_bounds__(128) void scanB(int* tot) {
  __shared__ int sh[128];
  int* tp = tot + blockIdx.x * 128;
  const int t = threadIdx.x;
  const int v = (t < kNCHUNK) ? tp[t] : 0;
  sh[t] = v;
  __syncthreads();
  for (int o = 1; o < 128; o <<= 1) {
    const int y = (t >= o) ? sh[t - o] : 0;
    __syncthreads();
    sh[t] += y;
    __syncthreads();
  }
  if (t < kNCHUNK) tp[t] = sh[t] - v;  // exclusive
}

__global__ __launch_bounds__(1024) void scanC(int* ptr_u, int* ptr_i,
                                              const int* __restrict__ tot,
                                              int* cur_u, int* cur_i) {
  const int dir = blockIdx.y;
  int* ptr = dir ? ptr_i : ptr_u;
  int* cur = dir ? cur_i : cur_u;
  const int i = blockIdx.x * 1024 + threadIdx.x;
  if (i < kNU) {
    const int v = ptr[i] + tot[dir * 128 + blockIdx.x];
    ptr[i] = v;
    cur[i] = v;
  }
}

// ------- projection body: relu(x @ Wp + b) -> fp32, 3-split bf16 MFMA -------
template <int F>
__device__ __forceinline__ void proj_body(
    const float* __restrict__ x, const unsigned short* __restrict__ Wh,
    const unsigned short* __restrict__ Wm, const unsigned short* __restrict__ Wl,
    const float* __restrict__ bias, float* __restrict__ out, int blk,
    unsigned short* sh) {
  constexpr int AS = F + 8, KC = F / 32;
  unsigned short* Ah = sh;
  unsigned short* Am = sh + kM * AS;
  unsigned short* Al = sh + 2 * kM * AS;
  const int tid = threadIdx.x;
  const size_t row0 = (size_t)blk * kM;
  for (int c = tid; c < kM * (F / 4); c += 256) {
    const int r = c / (F / 4), j = c % (F / 4);
    const float4 v = *(const float4*)&x[(row0 + r) * F + j * 4];
    const float* vv = &v.x;
    ushort4v h4, m4, l4;
#pragma unroll
    for (int u = 0; u < 4; ++u) {
      unsigned short th, tm, tl;
      split3(vv[u], th, tm, tl);
      h4[u] = th; m4[u] = tm; l4[u] = tl;
    }
    *(ushort4v*)&Ah[r * AS + j * 4] = h4;
    *(ushort4v*)&Am[r * AS + j * 4] = m4;
    *(ushort4v*)&Al[r * AS + j * 4] = l4;
  }
  const int lane = tid & 63, w = tid >> 6, q = lane >> 4, ln = lane & 15;
  floatx4 acc[2][2] = {}, accL[2][2] = {};
  __syncthreads();
#pragma unroll
  for (int kc = 0; kc < KC; ++kc) {
    bf16x8 bh[2], bm[2], bl_[2];
#pragma unroll
    for (int t = 0; t < 2; ++t) {
      const int off = (w * 32 + t * 16 + ln) * F + kc * 32 + q * 8;
      bh[t] = ldb8(&Wh[off]);
      bm[t] = ldb8(&Wm[off]);
      bl_[t] = ldb8(&Wl[off]);
    }
#pragma unroll
    for (int mt = 0; mt < 2; ++mt) {
      const int ro = mt * 16 + ln, co = kc * 32 + q * 8;
      const bf16x8 ah = ldb8(&Ah[ro * AS + co]);
      const bf16x8 am = ldb8(&Am[ro * AS + co]);
      const bf16x8 al = ldb8(&Al[ro * AS + co]);
#pragma unroll
      for (int t = 0; t < 2; ++t) {
        acc[mt][t] = mfma16(ah, bh[t], acc[mt][t]);  // full scale
        floatx4 cl = accL[mt][t];                    // low-order
        cl = mfma16(ah, bm[t], cl);
        cl = mfma16(am, bh[t], cl);
        cl = mfma16(ah, bl_[t], cl);
        cl = mfma16(al, bh[t], cl);
        cl = mfma16(am, bm[t], cl);
        accL[mt][t] = cl;
      }
    }
  }
#pragma unroll
  for (int t = 0; t < 2; ++t) {
    const int col = w * 32 + t * 16 + ln;
    const float bv = bias[col];
#pragma unroll
    for (int mt = 0; mt < 2; ++mt)
#pragma unroll
      for (int r = 0; r < 4; ++r)
        out[(row0 + mt * 16 + q * 4 + r) * kH + col] =
            fmaxf((acc[mt][t][r] + accL[mt][t][r]) + bv, 0.f);
  }
}

// --- heterogeneous kernel 1: edge-histogram blocks || user-projection -------
__global__ __launch_bounds__(256) void hist_proj(
    const int* __restrict__ eui, const int* __restrict__ eiu, int* cnt_i,
    int* cnt_u, const float* __restrict__ x,
    const unsigned short* __restrict__ Wh, const unsigned short* __restrict__ Wm,
    const unsigned short* __restrict__ Wl, const float* __restrict__ bias,
    float* __restrict__ out) {
  __shared__ __align__(16) unsigned short sh[3 * kM * (kFU + 8)];
  if (blockIdx.x < kEB) {  // histogram of edge destinations
    const int e = blockIdx.x * 256 + threadIdx.x;
    if (e < kE) {
      atomicAdd(&cnt_i[eui[kE + e]], 1);  // dst items
      atomicAdd(&cnt_u[eiu[kE + e]], 1);  // dst users
    }
  } else {  // user projection (F=96)
    proj_body<kFU>(x, Wh, Wm, Wl, bias, out, blockIdx.x - kEB, sh);
  }
}

// --- heterogeneous kernel 2: CSR fill blocks || item-projection -------------
__global__ __launch_bounds__(256) void fill_proj(
    const int* __restrict__ eui, const int* __restrict__ eiu, int* cur_i,
    int* cur_u, int* __restrict__ col_ui, int* __restrict__ col_iu,
    const float* __restrict__ x, const unsigned short* __restrict__ Wh,
    const unsigned short* __restrict__ Wm, const unsigned short* __restrict__ Wl,
    const float* __restrict__ bias, float* __restrict__ out) {
  __shared__ __align__(16) unsigned short sh[3 * kM * (kFI + 8)];
  if (blockIdx.x < kEB) {  // CSR column fill
    const int e = blockIdx.x * 256 + threadIdx.x;
    if (e < kE) {
      const int p = atomicAdd(&cur_i[eui[kE + e]], 1);
      col_ui[p] = eui[e];
      const int p2 = atomicAdd(&cur_u[eiu[kE + e]], 1);
      col_iu[p2] = eiu[e];
    }
  } else {  // item projection (F=160)
    proj_body<kFI>(x, Wh, Wm, Wl, bias, out, blockIdx.x - kEB, sh);
  }
}

// ------- gather-mean (fp32), both dirs, 4-way edge-unrolled for MLP ---------
struct AggArgs {
  const float* src[2];
  const int* ptr[2];
  const int* cur[2];
  const int* col[2];
  float* out[2];
};
template <int W>
__global__ __launch_bounds__(256) void agg2(AggArgs a) {
  const int dir = blockIdx.y;
  const int w = threadIdx.x >> 6, lane = threadIdx.x & 63;
  const int row = blockIdx.x * 4 + w;
  const float* __restrict__ feat = a.src[dir];
  const int* __restrict__ col = a.col[dir];
  const int beg = a.ptr[dir][row], end = a.cur[dir][row];
  const float inv = 1.0f / fmaxf((float)(end - beg), 1.0f);
  if (W == 128) {
    float s0 = 0.f, s1 = 0.f;
    int e = beg;
    for (; e + 4 <= end; e += 4) {  // 4 row-reads in flight
      const size_t c0 = col[e], c1 = col[e + 1], c2 = col[e + 2],
                   c3 = col[e + 3];
      const float2 v0 = *(const float2*)&feat[c0 * 128 + lane * 2];
      const float2 v1 = *(const float2*)&feat[c1 * 128 + lane * 2];
      const float2 v2 = *(const float2*)&feat[c2 * 128 + lane * 2];
      const float2 v3 = *(const float2*)&feat[c3 * 128 + lane * 2];
      s0 += v0.x; s1 += v0.y;
      s0 += v1.x; s1 += v1.y;
      s0 += v2.x; s1 += v2.y;
      s0 += v3.x; s1 += v3.y;
    }
    for (; e < end; ++e) {
      const float2 v = *(const float2*)&feat[(size_t)col[e] * 128 + lane * 2];
      s0 += v.x; s1 += v.y;
    }
    float2 o;
    o.x = s0 * inv;
    o.y = s1 * inv;
    *(float2*)&a.out[dir][(size_t)row * 128 + lane * 2] = o;
  } else {  // W == 64
    float s = 0.f;
    int e = beg;
    for (; e + 4 <= end; e += 4) {
      const size_t c0 = col[e], c1 = col[e + 1], c2 = col[e + 2],
                   c3 = col[e + 3];
      const float v0 = feat[c0 * 64 + lane];
      const float v1 = feat[c1 * 64 + lane];
      const float v2 = feat[c2 * 64 + lane];
      const float v3 = feat[c3 * 64 + lane];
      s += v0; s += v1; s += v2; s += v3;
    }
    for (; e < end; ++e) s += feat[(size_t)col[e] * 64 + lane];
    a.out[dir][(size_t)row * 64 + lane] = s * inv;
  }
}

// --- layer-0 SAGE: D = agg @ WL^T + root @ WR^T + bl; LN; ReLU --------------
// A-side 2-split (h,m), B-side 3-split. XOR-swizzled LDS (no bank conflicts).
// out may alias agg (same rows: reads complete in-block before writes).
struct FsArgs {
  const float* agg[2];
  const float* root[2];
  const unsigned short *WLh[2], *WLm[2], *WLl[2];
  const unsigned short *WRh[2], *WRm[2], *WRl[2];
  const float *bl[2], *g[2], *b[2];
  float* out[2];
};
__global__ __launch_bounds__(256) void sage0(FsArgs a) {
  constexpr int NOUT = 128;
  __shared__ __align__(16) unsigned short Ab[4 * kM * kH];  // 32 KB, 4 planes
  float* Cs = (float*)Ab;  // reused post-MFMA: [kM][NOUT+1] fp32
  const int tid = threadIdx.x;
  const int dir = blockIdx.y;
  const size_t row0 = (size_t)blockIdx.x * kM;
  const float* __restrict__ agg = a.agg[dir];
  const float* __restrict__ root = a.root[dir];

  // stage both A matrices, 2-split, swizzled
  for (int c = tid; c < 2048; c += 256) {
    const int mat = c >> 10, cc = c & 1023, r = cc >> 5, j = cc & 31;
    const float4 v = *(const float4*)((mat ? root : agg) + (row0 + r) * kH + j * 4);
    const float* vv = &v.x;
    ushort4v h4, m4;
#pragma unroll
    for (int u = 0; u < 4; ++u) {
      unsigned short th, tm;
      split2(vv[u], th, tm);
      h4[u] = th; m4[u] = tm;
    }
    *(ushort4v*)ab_ptr(Ab, mat * 2 + 0, r, j * 8) = h4;
    *(ushort4v*)ab_ptr(Ab, mat * 2 + 1, r, j * 8) = m4;
  }

  const int lane = tid & 63, w = tid >> 6, q = lane >> 4, ln = lane & 15;
  floatx4 acc[2][2] = {}, accL[2][2] = {};
  const unsigned short* __restrict__ WLh = a.WLh[dir];
  const unsigned short* __restrict__ WLm = a.WLm[dir];
  const unsigned short* __restrict__ WLl = a.WLl[dir];
  const unsigned short* __restrict__ WRh = a.WRh[dir];
  const unsigned short* __restrict__ WRm = a.WRm[dir];
  const unsigned short* __restrict__ WRl = a.WRl[dir];
  __syncthreads();
#pragma unroll
  for (int kc = 0; kc < 4; ++kc) {
    bf16x8 BL[3][2], BR[3][2];
#pragma unroll
    for (int t = 0; t < 2; ++t) {
      const int off = (w * 32 + t * 16 + ln) * kH + kc * 32 + q * 8;
      BL[0][t] = ldb8(&WLh[off]);
      BL[1][t] = ldb8(&WLm[off]);
      BL[2][t] = ldb8(&WLl[off]);
      BR[0][t] = ldb8(&WRh[off]);
      BR[1][t] = ldb8(&WRm[off]);
      BR[2][t] = ldb8(&WRl[off]);
    }
#pragma unroll
    for (int mt = 0; mt < 2; ++mt) {
      const int ro = mt * 16 + ln, cob = kc * 64 + q * 16;
      const bf16x8 a1h = ldb8(ab_ptr(Ab, 0, ro, cob));
      const bf16x8 a1m = ldb8(ab_ptr(Ab, 1, ro, cob));
      const bf16x8 a2h = ldb8(ab_ptr(Ab, 2, ro, cob));
      const bf16x8 a2m = ldb8(ab_ptr(Ab, 3, ro, cob));
#pragma unroll
      for (int t = 0; t < 2; ++t) {
        floatx4 c = acc[mt][t];  // full-scale h*h terms
        c = mfma16(a1h, BL[0][t], c);
        c = mfma16(a2h, BR[0][t], c);
        acc[mt][t] = c;
        floatx4 cl = accL[mt][t];  // low-order terms
        cl = mfma16(a1h, BL[1][t], cl);
        cl = mfma16(a1m, BL[0][t], cl);
        cl = mfma16(a1h, BL[2][t], cl);
        cl = mfma16(a1m, BL[1][t], cl);
        cl = mfma16(a2h, BR[1][t], cl);
        cl = mfma16(a2m, BR[0][t], cl);
        cl = mfma16(a2h, BR[2][t], cl);
        cl = mfma16(a2m, BR[1][t], cl);
        accL[mt][t] = cl;
      }
    }
  }
  __syncthreads();  // done reading Ab; safe to overwrite with Cs
  const float* __restrict__ blv = a.bl[dir];
#pragma unroll
  for (int t = 0; t < 2; ++t) {
    const int colx = (w * 2 + t) * 16 + ln;
    const float bv = blv[colx];
#pragma unroll
    for (int mt = 0; mt < 2; ++mt)
#pragma unroll
      for (int r = 0; r < 4; ++r)
        Cs[(mt * 16 + q * 4 + r) * (NOUT + 1) + colx] =
            (acc[mt][t][r] + accL[mt][t][r]) + bv;
  }
  __syncthreads();
  // Two-pass LayerNorm: 8 threads/row, 16 cols each; ReLU
  const int r = tid >> 3, sub = tid & 7;
  const float* __restrict__ gg = a.g[dir];
  const float* __restrict__ bb = a.b[dir];
  float vals[16], s = 0.f;
#pragma unroll
  for (int j = 0; j < 16; ++j) {
    const float v = Cs[r * (NOUT + 1) + sub * 16 + j];
    vals[j] = v;
    s += v;
  }
#pragma unroll
  for (int o = 1; o < 8; o <<= 1) s += __shfl_xor(s, o, 64);
  const float mean = s * (1.0f / NOUT);
  float s2 = 0.f;
#pragma unroll
  for (int j = 0; j < 16; ++j) {
    const float d = vals[j] - mean;
    s2 += d * d;
  }
#pragma unroll
  for (int o = 1; o < 8; o <<= 1) s2 += __shfl_xor(s2, o, 64);
  const float rstd = rsqrtf(s2 * (1.0f / NOUT) + kEPS);
  float* op = a.out[dir] + (row0 + r) * NOUT + sub * 16;
#pragma unroll
  for (int j = 0; j < 16; j += 4) {
    float4 o4;
    float* oo = &o4.x;
#pragma unroll
    for (int jj = 0; jj < 4; ++jj)
      oo[jj] = fmaxf((vals[j + jj] - mean) * rstd * gg[sub * 16 + j + jj] +
                         bb[sub * 16 + j + jj],
                     0.f);
    *(float4*)&op[j] = o4;
  }
}

// --- layer-1 pre-projection: Z = X @ Wl1 (128 -> 64), no bias ---------------
struct ZArgs {
  const float* src[2];
  const unsigned short *Bh[2], *Bm[2], *Bl[2];
  float* out[2];
};
__global__ __launch_bounds__(256) void zproj(ZArgs a) {
  __shared__ __align__(16) unsigned short Ab[2 * kM * kH];  // 16 KB
  const int tid = threadIdx.x, dir = blockIdx.y;
  const size_t row0 = (size_t)blockIdx.x * kM;
  const float* __restrict__ src = a.src[dir];
  for (int c = tid; c < 1024; c += 256) {
    const int r = c >> 5, j = c & 31;
    const float4 v = *(const float4*)&src[(row0 + r) * kH + j * 4];
    const float* vv = &v.x;
    ushort4v h4, m4;
#pragma unroll
    for (int u = 0; u < 4; ++u) {
      unsigned short th, tm;
      split2(vv[u], th, tm);
      h4[u] = th; m4[u] = tm;
    }
    *(ushort4v*)ab_ptr(Ab, 0, r, j * 8) = h4;
    *(ushort4v*)ab_ptr(Ab, 1, r, j * 8) = m4;
  }
  const int lane = tid & 63, w = tid >> 6, q = lane >> 4, ln = lane & 15;
  const unsigned short* __restrict__ Bh = a.Bh[dir];
  const unsigned short* __restrict__ Bm = a.Bm[dir];
  const unsigned short* __restrict__ Bl = a.Bl[dir];
  floatx4 acc[2] = {}, accL[2] = {};
  __syncthreads();
#pragma unroll
  for (int kc = 0; kc < 4; ++kc) {
    const int off = (w * 16 + ln) * kH + kc * 32 + q * 8;
    const bf16x8 bh = ldb8(&Bh[off]);
    const bf16x8 bm = ldb8(&Bm[off]);
    const bf16x8 bl_ = ldb8(&Bl[off]);
#pragma unroll
    for (int mt = 0; mt < 2; ++mt) {
      const int ro = mt * 16 + ln, cob = kc * 64 + q * 16;
      const bf16x8 ah = ldb8(ab_ptr(Ab, 0, ro, cob));
      const bf16x8 am = ldb8(ab_ptr(Ab, 1, ro, cob));
      acc[mt] = mfma16(ah, bh, acc[mt]);
      floatx4 cl = accL[mt];
      cl = mfma16(ah, bm, cl);
      cl = mfma16(am, bh, cl);
      cl = mfma16(ah, bl_, cl);
      cl = mfma16(am, bm, cl);
      accL[mt] = cl;
    }
  }
  float* __restrict__ out = a.out[dir];
  const int col = w * 16 + ln;
#pragma unroll
  for (int mt = 0; mt < 2; ++mt)
#pragma unroll
    for (int r = 0; r < 4; ++r)
      out[(row0 + mt * 16 + q * 4 + r) * kOUT + col] =
          acc[mt][r] + accL[mt][r];
}

// --- layer-1 SAGE finish: D = root @ Wr1 + bl + aggz; LN (no ReLU) ----------
struct S1Args {
  const float* root[2];
  const float* aggz[2];
  const unsigned short *Bh[2], *Bm[2], *Bl[2];
  const float *bl[2], *g[2], *b[2];
  float* out[2];
};
__global__ __launch_bounds__(256) void sage1(S1Args a) {
  constexpr int NOUT = kOUT;
  __shared__ __align__(16) unsigned short Ab[2 * kM * kH];  // 16 KB
  float* Cs = (float*)Ab;  // reused post-MFMA: [kM][NOUT+1]
  const int tid = threadIdx.x, dir = blockIdx.y;
  const size_t row0 = (size_t)blockIdx.x * kM;
  const float* __restrict__ root = a.root[dir];
  for (int c = tid; c < 1024; c += 256) {
    const int r = c >> 5, j = c & 31;
    const float4 v = *(const float4*)&root[(row0 + r) * kH + j * 4];
    const float* vv = &v.x;
    ushort4v h4, m4;
#pragma unroll
    for (int u = 0; u < 4; ++u) {
      unsigned short th, tm;
      split2(vv[u], th, tm);
      h4[u] = th; m4[u] = tm;
    }
    *(ushort4v*)ab_ptr(Ab, 0, r, j * 8) = h4;
    *(ushort4v*)ab_ptr(Ab, 1, r, j * 8) = m4;
  }
  const int lane = tid & 63, w = tid >> 6, q = lane >> 4, ln = lane & 15;
  const unsigned short* __restrict__ Bh = a.Bh[dir];
  const unsigned short* __restrict__ Bm = a.Bm[dir];
  const unsigned short* __restrict__ Bl = a.Bl[dir];
  floatx4 acc[2] = {}, accL[2] = {};
  __syncthreads();
#pragma unroll
  for (int kc = 0; kc < 4; ++kc) {
    const int off = (w * 16 + ln) * kH + kc * 32 + q * 8;
    const bf16x8 bh = ldb8(&Bh[off]);
    const bf16x8 bm = ldb8(&Bm[off]);
    const bf16x8 bl_ = ldb8(&Bl[off]);
#pragma unroll
    for (int mt = 0; mt < 2; ++mt) {
      const int ro = mt * 16 + ln, cob = kc * 64 + q * 16;
      const bf16x8 ah = ldb8(ab_ptr(Ab, 0, ro, cob));
      const bf16x8 am = ldb8(ab_ptr(Ab, 1, ro, cob));
      acc[mt] = mfma16(ah, bh, acc[mt]);
      floatx4 cl = accL[mt];
      cl = mfma16(ah, bm, cl);
      cl = mfma16(am, bh, cl);
      cl = mfma16(ah, bl_, cl);
      cl = mfma16(am, bm, cl);
      accL[mt] = cl;
    }
  }
  __syncthreads();  // done reading Ab
  const float* __restrict__ blv = a.bl[dir];
  {
    const int col = w * 16 + ln;
    const float bv = blv[col];
#pragma unroll
    for (int mt = 0; mt < 2; ++mt)
#pragma unroll
      for (int r = 0; r < 4; ++r)
        Cs[(mt * 16 + q * 4 + r) * (NOUT + 1) + col] =
            (acc[mt][r] + accL[mt][r]) + bv;
  }
  __syncthreads();
  // LN over 64 cols: 8 threads/row, 8 cols each; add gathered term from global
  const int r = tid >> 3, sub = tid & 7;
  const float* __restrict__ az = a.aggz[dir];
  const float* __restrict__ gg = a.g[dir];
  const float* __restrict__ bb = a.b[dir];
  float vals[8], s = 0.f;
#pragma unroll
  for (int j = 0; j < 8; ++j) {
    const float v = Cs[r * (NOUT + 1) + sub * 8 + j] +
                    az[(row0 + r) * NOUT + sub * 8 + j];
    vals[j] = v;
    s += v;
  }
#pragma unroll
  for (int o = 1; o < 8; o <<= 1) s += __shfl_xor(s, o, 64);
  const float mean = s * (1.0f / NOUT);
  float s2 = 0.f;
#pragma unroll
  for (int j = 0; j < 8; ++j) {
    const float d = vals[j] - mean;
    s2 += d * d;
  }
#pragma unroll
  for (int o = 1; o < 8; o <<= 1) s2 += __shfl_xor(s2, o, 64);
  const float rstd = rsqrtf(s2 * (1.0f / NOUT) + kEPS);
  float* op = a.out[dir] + (row0 + r) * NOUT + sub * 8;
#pragma unroll
  for (int j = 0; j < 8; j += 4) {
    float4 o4;
    float* oo = &o4.x;
#pragma unroll
    for (int jj = 0; jj < 4; ++jj)
      oo[jj] = (vals[j + jj] - mean) * rstd * gg[sub * 8 + j + jj] +
               bb[sub * 8 + j + jj];
    *(float4*)&op[j] = o4;
  }
}

extern "C" void kernel_launch(void* const* d_in, const int* in_sizes, int n_in,
                              void* d_out, int out_size, void* d_ws, size_t ws_size,
                              hipStream_t stream) {
  (void)in_sizes; (void)n_in; (void)out_size; (void)ws_size;
  const float* x_u    = (const float*)d_in[0];
  const float* x_i    = (const float*)d_in[1];
  const int*   e_ui   = (const int*)d_in[2];
  const int*   e_iu   = (const int*)d_in[3];
  const float* Wp_u   = (const float*)d_in[4];
  const float* bp_u   = (const float*)d_in[5];
  const float* Wp_i   = (const float*)d_in[6];
  const float* bp_i   = (const float*)d_in[7];
  const float* Wl0_ui = (const float*)d_in[8];
  const float* bl0_ui = (const float*)d_in[9];
  const float* Wr0_ui = (const float*)d_in[10];
  const float* Wl0_iu = (const float*)d_in[11];
  const float* bl0_iu = (const float*)d_in[12];
  const float* Wr0_iu = (const float*)d_in[13];
  const float* g0_u   = (const float*)d_in[14];
  const float* b0_u   = (const float*)d_in[15];
  const float* g0_i   = (const float*)d_in[16];
  const float* b0_i   = (const float*)d_in[17];
  const float* Wl1_ui = (const float*)d_in[18];
  const float* bl1_ui = (const float*)d_in[19];
  const float* Wr1_ui = (const float*)d_in[20];
  const float* Wl1_iu = (const float*)d_in[21];
  const float* bl1_iu = (const float*)d_in[22];
  const float* Wr1_iu = (const float*)d_in[23];
  const float* g1_u   = (const float*)d_in[24];
  const float* b1_u   = (const float*)d_in[25];
  const float* g1_i   = (const float*)d_in[26];
  const float* b1_i   = (const float*)d_in[27];

  // ---- workspace layout ----
  float* pf = (float*)d_ws;
  const size_t NH = (size_t)kNU * kH;  // 12.8M floats
  float* hu0 = pf;           // projected user feats (later: Zu | Zi)
  float* hi0 = pf + NH;      // projected item feats (later: aggzI | aggzU)
  float* b2  = pf + 2 * NH;  // aggI -> h_i1 (in-place)
  float* b3  = pf + 3 * NH;  // aggU -> h_u1 (in-place)
  float* Zu = hu0;
  float* Zi = hu0 + (size_t)kNU * kOUT;
  float* aggzI = hi0;
  float* aggzU = hi0 + (size_t)kNU * kOUT;
  unsigned short* wh = (unsigned short*)(pf + 4 * NH);  // 131072 ushorts each
  unsigned short* wm = wh + 131072;
  unsigned short* wl = wm + 131072;
  int* pi = (int*)(wl + 131072);
  int* cnt_u = pi; pi += kNU;
  int* cnt_i = pi; pi += kNU;
  int* ptr_u = pi; pi += kNU;
  int* ptr_i = pi; pi += kNU;
  int* cur_u = pi; pi += kNU;
  int* cur_i = pi; pi += kNU;
  int* tot   = pi; pi += 2 * 128;
  int* col_ui = pi; pi += kE;
  int* col_iu = pi; pi += kE;

  // weight sub-offsets (identical layout in h/m/l sets)
  const int oPu = 0, oPi = 12288, o0Lui = 32768, o0Rui = 49152,
            o0Liu = 65536, o0Riu = 81920, o1Lui = 98304, o1Rui = 106496,
            o1Liu = 114688, o1Riu = 122880;

  float* out_u = (float*)d_out;               // h_u2: [100000][64]
  float* out_i = out_u + (size_t)kNU * kOUT;  // h_i2: [100000][64]

  // ---- weight convert/transpose/3-split ----
  WcvtArgs wa;
  const float* wsrc[10] = {Wp_u, Wp_i, Wl0_ui, Wr0_ui, Wl0_iu, Wr0_iu,
                           Wl1_ui, Wr1_ui, Wl1_iu, Wr1_iu};
  const int woff[10] = {oPu, oPi, o0Lui, o0Rui, o0Liu, o0Riu,
                        o1Lui, o1Rui, o1Liu, o1Riu};
  const int wK[10] = {kFU, kFI, kH, kH, kH, kH, kH, kH, kH, kH};
  const int wN[10] = {kH, kH, kH, kH, kH, kH, kOUT, kOUT, kOUT, kOUT};
  for (int i = 0; i < 10; ++i) {
    wa.src[i] = wsrc[i];
    wa.dh[i] = wh + woff[i];
    wa.dm[i] = wm + woff[i];
    wa.dl[i] = wl + woff[i];
    wa.K[i] = wK[i];
    wa.N[i] = wN[i];
  }
  wcvt<<<dim3(80, 10), 256, 0, stream>>>(wa);

  // ---- CSR build overlapped with projections ----
  zero_int<<<256, 256, 0, stream>>>(cnt_u, 2 * kNU);
  hist_proj<<<kEB + kNBLK, 256, 0, stream>>>(e_ui, e_iu, cnt_i, cnt_u, x_u,
                                             wh + oPu, wm + oPu, wl + oPu,
                                             bp_u, hu0);
  scanA<<<dim3(kNCHUNK, 2), 1024, 0, stream>>>(cnt_u, cnt_i, ptr_u, ptr_i, tot);
  scanB<<<2, 128, 0, stream>>>(tot);
  scanC<<<dim3(kNCHUNK, 2), 1024, 0, stream>>>(ptr_u, ptr_i, tot, cur_u, cur_i);
  fill_proj<<<kEB + kNBLK, 256, 0, stream>>>(e_ui, e_iu, cur_i, cur_u, col_ui,
                                             col_iu, x_i, wh + oPi, wm + oPi,
                                             wl + oPi, bp_i, hi0);

  // ---- layer 0: gather (both dirs) then SAGE (both dirs) ----
  AggArgs g0;
  g0.src[0] = hu0; g0.ptr[0] = ptr_i; g0.cur[0] = cur_i; g0.col[0] = col_ui;
  g0.out[0] = b2;
  g0.src[1] = hi0; g0.ptr[1] = ptr_u; g0.cur[1] = cur_u; g0.col[1] = col_iu;
  g0.out[1] = b3;
  agg2<kH><<<dim3(kNU / 4, 2), 256, 0, stream>>>(g0);

  FsArgs a0;
  a0.agg[0] = b2; a0.root[0] = hi0;
  a0.WLh[0] = wh + o0Lui; a0.WLm[0] = wm + o0Lui; a0.WLl[0] = wl + o0Lui;
  a0.WRh[0] = wh + o0Rui; a0.WRm[0] = wm + o0Rui; a0.WRl[0] = wl + o0Rui;
  a0.bl[0] = bl0_ui; a0.g[0] = g0_i; a0.b[0] = b0_i; a0.out[0] = b2;  // h_i1
  a0.agg[1] = b3; a0.root[1] = hu0;
  a0.WLh[1] = wh + o0Liu; a0.WLm[1] = wm + o0Liu; a0.WLl[1] = wl + o0Liu;
  a0.WRh[1] = wh + o0Riu; a0.WRm[1] = wm + o0Riu; a0.WRl[1] = wl + o0Riu;
  a0.bl[1] = bl0_iu; a0.g[1] = g0_u; a0.b[1] = b0_u; a0.out[1] = b3;  // h_u1
  sage0<<<dim3(kNBLK, 2), 256, 0, stream>>>(a0);

  // ---- layer 1: pre-project Z = h1 @ Wl1 (64-wide), gather Z, finish ----
  ZArgs zp;
  zp.src[0] = b3;  // h_u1 -> Zu (for item aggregation)
  zp.Bh[0] = wh + o1Lui; zp.Bm[0] = wm + o1Lui; zp.Bl[0] = wl + o1Lui;
  zp.out[0] = Zu;
  zp.src[1] = b2;  // h_i1 -> Zi (for user aggregation)
  zp.Bh[1] = wh + o1Liu; zp.Bm[1] = wm + o1Liu; zp.Bl[1] = wl + o1Liu;
  zp.out[1] = Zi;
  zproj<<<dim3(kNBLK, 2), 256, 0, stream>>>(zp);

  AggArgs g1;
  g1.src[0] = Zu; g1.ptr[0] = ptr_i; g1.cur[0] = cur_i; g1.col[0] = col_ui;
  g1.out[0] = aggzI;
  g1.src[1] = Zi; g1.ptr[1] = ptr_u; g1.cur[1] = cur_u; g1.col[1] = col_iu;
  g1.out[1] = aggzU;
  agg2<kOUT><<<dim3(kNU / 4, 2), 256, 0, stream>>>(g1);

  S1Args s1;
  s1.root[0] = b2; s1.aggz[0] = aggzI;
  s1.Bh[0] = wh + o1Rui; s1.Bm[0] = wm + o1Rui; s1.Bl[0] = wl + o1Rui;
  s1.bl[0] = bl1_ui; s1.g[0] = g1_i; s1.b[0] = b1_i; s1.out[0] = out_i;
  s1.root[1] = b3; s1.aggz[1] = aggzU;
  s1.Bh[1] = wh + o1Riu; s1.Bm[1] = wm + o1Riu; s1.Bl[1] = wl + o1Riu;
  s1.bl[1] = bl1_iu; s1.g[1] = g1_u; s1.b[1] = b1_u; s1.out[1] = out_u;
  sage1<<<dim3(kNBLK, 2), 256, 0, stream>>>(s1);
}

// Round 4
// 774.744 us; speedup vs baseline: 1.5164x; 1.0536x over previous
//
#include <hip/hip_runtime.h>

typedef __attribute__((ext_vector_type(8))) __bf16 bf16x8;
typedef __attribute__((ext_vector_type(4))) float floatx4;
typedef __attribute__((ext_vector_type(8))) unsigned short ushort8v;
typedef __attribute__((ext_vector_type(4))) unsigned short ushort4v;

namespace {
constexpr int kNU = 100000, kNI = 100000, kE = 600000;
constexpr int kFU = 96, kFI = 160, kH = 128, kOUT = 64;
constexpr float kEPS = 1e-5f;
constexpr int kM = 32;                 // rows per block in MFMA kernels
constexpr int kNCHUNK = 98;            // ceil(100000 / 1024)
constexpr int kNBLK = kNU / kM;        // 3125 row-blocks per node type
constexpr int kEB = (kE + 255) / 256;  // 2344 edge-slices
constexpr int kPART = kNU / 8;         // dst-id range per XCD partition
}

__device__ __forceinline__ unsigned short f2b(float f) {  // fp32 -> bf16 RNE
  unsigned u = __builtin_bit_cast(unsigned, f);
  u += 0x7FFFu + ((u >> 16) & 1u);
  return (unsigned short)(u >> 16);
}
__device__ __forceinline__ float b2f(unsigned short h) {
  return __builtin_bit_cast(float, (unsigned)h << 16);
}
// 3-way bf16 split: v = h + m + l, residual <= ~2^-27 |v|
__device__ __forceinline__ void split3(float v, unsigned short& h,
                                       unsigned short& m, unsigned short& l) {
  h = f2b(v);
  const float r1 = v - b2f(h);   // exact
  m = f2b(r1);
  const float r2 = r1 - b2f(m);  // exact
  l = f2b(r2);
}
// 2-way bf16 split: v = h + m, residual <= ~2^-18 |v|
__device__ __forceinline__ void split2(float v, unsigned short& h,
                                       unsigned short& m) {
  h = f2b(v);
  m = f2b(v - b2f(h));
}
__device__ __forceinline__ bf16x8 ldb8(const unsigned short* p) {
  return __builtin_bit_cast(bf16x8, *(const ushort8v*)p);
}
__device__ __forceinline__ floatx4 mfma16(bf16x8 a, bf16x8 b, floatx4 c) {
  return __builtin_amdgcn_mfma_f32_16x16x32_bf16(a, b, c, 0, 0, 0);
}
// Swizzled LDS accessor: plane stride 8 KB, row stride 256 B, XOR bank swizzle
__device__ __forceinline__ unsigned short* ab_ptr(unsigned short* base,
                                                  int plane, int r, int bo) {
  return (unsigned short*)((char*)base + plane * 8192 + r * 256 +
                           (bo ^ ((r & 7) << 4)));
}

// --- weight convert+transpose+3-split: Wh/Wm/Wl[n][k] = split(W[k][n]) ------
struct WcvtArgs {
  const float* src[10];
  unsigned short* dh[10];
  unsigned short* dm[10];
  unsigned short* dl[10];
  int K[10], N[10];
};
__global__ __launch_bounds__(256) void wcvt(WcvtArgs a) {
  const int m = blockIdx.y;
  const int K = a.K[m], N = a.N[m];
  const int idx = blockIdx.x * 256 + threadIdx.x;
  if (idx < K * N) {
    const int n = idx / K, k = idx - n * K;
    unsigned short h, mm, l;
    split3(a.src[m][(size_t)k * N + n], h, mm, l);
    a.dh[m][idx] = h;
    a.dm[m][idx] = mm;
    a.dl[m][idx] = l;
  }
}

// ---------------- CSR build -------------------------------------------------
__global__ void zero_int(int* __restrict__ p, int n) {
  int i = blockIdx.x * blockDim.x + threadIdx.x;
  const int st = gridDim.x * blockDim.x;
  for (; i < n; i += st) p[i] = 0;
}

// exclusive scan within 1024-chunk; chunk totals to tot[dir*128 + chunk]
__global__ __launch_bounds__(1024) void scanA(const int* __restrict__ cnt_u,
                                              const int* __restrict__ cnt_i,
                                              int* ptr_u, int* ptr_i, int* tot) {
  __shared__ int sh[1024];
  const int dir = blockIdx.y;
  const int* cnt = dir ? cnt_i : cnt_u;
  int* ptr = dir ? ptr_i : ptr_u;
  const int t = threadIdx.x;
  const int i = blockIdx.x * 1024 + t;
  const int v = (i < kNU) ? cnt[i] : 0;
  sh[t] = v;
  __syncthreads();
  for (int o = 1; o < 1024; o <<= 1) {
    const int y = (t >= o) ? sh[t - o] : 0;
    __syncthreads();
    sh[t] += y;
    __syncthreads();
  }
  if (i < kNU) ptr[i] = sh[t] - v;  // exclusive within chunk
  if (t == 1023) tot[dir * 128 + blockIdx.x] = sh[1023];
}

// exclusive scan of the (<=98) chunk totals; one block per direction
__global__ __launch_bounds__(128) void scanB(int* tot) {
  __shared__ int sh[128];
  int* tp = tot + blockIdx.x * 128;
  const int t = threadIdx.x;
  const int v = (t < kNCHUNK) ? tp[t] : 0;
  sh[t] = v;
  __syncthreads();
  for (int o = 1; o < 128; o <<= 1) {
    const int y = (t >= o) ? sh[t - o] : 0;
    __syncthreads();
    sh[t] += y;
    __syncthreads();
  }
  if (t < kNCHUNK) tp[t] = sh[t] - v;  // exclusive
}

__global__ __launch_bounds__(1024) void scanC(int* ptr_u, int* ptr_i,
                                              const int* __restrict__ tot,
                                              int* cur_u, int* cur_i) {
  const int dir = blockIdx.y;
  int* ptr = dir ? ptr_i : ptr_u;
  int* cur = dir ? cur_i : cur_u;
  const int i = blockIdx.x * 1024 + threadIdx.x;
  if (i < kNU) {
    const int v = ptr[i] + tot[dir * 128 + blockIdx.x];
    ptr[i] = v;
    cur[i] = v;
  }
}

// ------- projection body: relu(x @ Wp + b) -> fp32, 3-split bf16 MFMA -------
template <int F>
__device__ __forceinline__ void proj_body(
    const float* __restrict__ x, const unsigned short* __restrict__ Wh,
    const unsigned short* __restrict__ Wm, const unsigned short* __restrict__ Wl,
    const float* __restrict__ bias, float* __restrict__ out, int blk,
    unsigned short* sh) {
  constexpr int AS = F + 8, KC = F / 32;
  unsigned short* Ah = sh;
  unsigned short* Am = sh + kM * AS;
  unsigned short* Al = sh + 2 * kM * AS;
  const int tid = threadIdx.x;
  const size_t row0 = (size_t)blk * kM;
  for (int c = tid; c < kM * (F / 4); c += 256) {
    const int r = c / (F / 4), j = c % (F / 4);
    const float4 v = *(const float4*)&x[(row0 + r) * F + j * 4];
    const float* vv = &v.x;
    ushort4v h4, m4, l4;
#pragma unroll
    for (int u = 0; u < 4; ++u) {
      unsigned short th, tm, tl;
      split3(vv[u], th, tm, tl);
      h4[u] = th; m4[u] = tm; l4[u] = tl;
    }
    *(ushort4v*)&Ah[r * AS + j * 4] = h4;
    *(ushort4v*)&Am[r * AS + j * 4] = m4;
    *(ushort4v*)&Al[r * AS + j * 4] = l4;
  }
  const int lane = tid & 63, w = tid >> 6, q = lane >> 4, ln = lane & 15;
  floatx4 acc[2][2] = {}, accL[2][2] = {};
  __syncthreads();
#pragma unroll
  for (int kc = 0; kc < KC; ++kc) {
    bf16x8 bh[2], bm[2], bl_[2];
#pragma unroll
    for (int t = 0; t < 2; ++t) {
      const int off = (w * 32 + t * 16 + ln) * F + kc * 32 + q * 8;
      bh[t] = ldb8(&Wh[off]);
      bm[t] = ldb8(&Wm[off]);
      bl_[t] = ldb8(&Wl[off]);
    }
#pragma unroll
    for (int mt = 0; mt < 2; ++mt) {
      const int ro = mt * 16 + ln, co = kc * 32 + q * 8;
      const bf16x8 ah = ldb8(&Ah[ro * AS + co]);
      const bf16x8 am = ldb8(&Am[ro * AS + co]);
      const bf16x8 al = ldb8(&Al[ro * AS + co]);
#pragma unroll
      for (int t = 0; t < 2; ++t) {
        acc[mt][t] = mfma16(ah, bh[t], acc[mt][t]);  // full scale
        floatx4 cl = accL[mt][t];                    // low-order
        cl = mfma16(ah, bm[t], cl);
        cl = mfma16(am, bh[t], cl);
        cl = mfma16(ah, bl_[t], cl);
        cl = mfma16(al, bh[t], cl);
        cl = mfma16(am, bm[t], cl);
        accL[mt][t] = cl;
      }
    }
  }
#pragma unroll
  for (int t = 0; t < 2; ++t) {
    const int col = w * 32 + t * 16 + ln;
    const float bv = bias[col];
#pragma unroll
    for (int mt = 0; mt < 2; ++mt)
#pragma unroll
      for (int r = 0; r < 4; ++r)
        out[(row0 + mt * 16 + q * 4 + r) * kH + col] =
            fmaxf((acc[mt][t][r] + accL[mt][t][r]) + bv, 0.f);
  }
}

// --- het kernel 1: XCD-partitioned edge-histogram || user-projection --------
// Edge blocks: 8 partition-copies per edge-slice; partition p = blockIdx&7
// (~XCD under round-robin dispatch) handles dst ids in [p*kPART,(p+1)*kPART),
// so each 64B counter line is only touched from one XCD's L2.
__global__ __launch_bounds__(256, 4) void hist_proj(
    const int* __restrict__ eui, const int* __restrict__ eiu, int* cnt_i,
    int* cnt_u, const float* __restrict__ x,
    const unsigned short* __restrict__ Wh, const unsigned short* __restrict__ Wm,
    const unsigned short* __restrict__ Wl, const float* __restrict__ bias,
    float* __restrict__ out) {
  __shared__ __align__(16) unsigned short sh[3 * kM * (kFU + 8)];
  if (blockIdx.x < 8 * kEB) {
    const int part = blockIdx.x & 7, slice = blockIdx.x >> 3;
    const int e = slice * 256 + threadIdx.x;
    if (e < kE) {
      const int di = eui[kE + e];  // dst item
      if (di / kPART == part) atomicAdd(&cnt_i[di], 1);
      const int du = eiu[kE + e];  // dst user
      if (du / kPART == part) atomicAdd(&cnt_u[du], 1);
    }
  } else {  // user projection (F=96)
    proj_body<kFU>(x, Wh, Wm, Wl, bias, out, blockIdx.x - 8 * kEB, sh);
  }
}

// --- het kernel 2: XCD-partitioned CSR fill || item-projection --------------
__global__ __launch_bounds__(256, 4) void fill_proj(
    const int* __restrict__ eui, const int* __restrict__ eiu, int* cur_i,
    int* cur_u, int* __restrict__ col_ui, int* __restrict__ col_iu,
    const float* __restrict__ x, const unsigned short* __restrict__ Wh,
    const unsigned short* __restrict__ Wm, const unsigned short* __restrict__ Wl,
    const float* __restrict__ bias, float* __restrict__ out) {
  __shared__ __align__(16) unsigned short sh[3 * kM * (kFI + 8)];
  if (blockIdx.x < 8 * kEB) {
    const int part = blockIdx.x & 7, slice = blockIdx.x >> 3;
    const int e = slice * 256 + threadIdx.x;
    if (e < kE) {
      const int di = eui[kE + e];
      if (di / kPART == part) {
        const int p = atomicAdd(&cur_i[di], 1);
        col_ui[p] = eui[e];
      }
      const int du = eiu[kE + e];
      if (du / kPART == part) {
        const int p2 = atomicAdd(&cur_u[du], 1);
        col_iu[p2] = eiu[e];
      }
    }
  } else {  // item projection (F=160)
    proj_body<kFI>(x, Wh, Wm, Wl, bias, out, blockIdx.x - 8 * kEB, sh);
  }
}

// ------- gather-mean (fp32), both dirs, batched-8 loads for MLP -------------
struct AggArgs {
  const float* src[2];
  const int* ptr[2];
  const int* cur[2];
  const int* col[2];
  float* out[2];
};
template <int W>
__global__ __launch_bounds__(256) void agg2(AggArgs a) {
  const int dir = blockIdx.y;
  const int w = threadIdx.x >> 6, lane = threadIdx.x & 63;
  const int row = blockIdx.x * 4 + w;
  const float* __restrict__ feat = a.src[dir];
  const int* __restrict__ col = a.col[dir];
  const int beg = a.ptr[dir][row], end = a.cur[dir][row];
  const float inv = 1.0f / fmaxf((float)(end - beg), 1.0f);
  if (W == 128) {
    float s0 = 0.f, s1 = 0.f;
    for (int e = beg; e < end; e += 8) {
      const int n = end - e;  // uniform across wave
      float2 v[8];
#pragma unroll
      for (int j = 0; j < 8; ++j)
        if (j < n) v[j] = *(const float2*)&feat[(size_t)col[e + j] * 128 + lane * 2];
#pragma unroll
      for (int j = 0; j < 8; ++j)
        if (j < n) { s0 += v[j].x; s1 += v[j].y; }
    }
    float2 o;
    o.x = s0 * inv;
    o.y = s1 * inv;
    *(float2*)&a.out[dir][(size_t)row * 128 + lane * 2] = o;
  } else {  // W == 64
    float s = 0.f;
    for (int e = beg; e < end; e += 8) {
      const int n = end - e;
      float v[8];
#pragma unroll
      for (int j = 0; j < 8; ++j)
        if (j < n) v[j] = feat[(size_t)col[e + j] * 64 + lane];
#pragma unroll
      for (int j = 0; j < 8; ++j)
        if (j < n) s += v[j];
    }
    a.out[dir][(size_t)row * 64 + lane] = s * inv;
  }
}

// --- layer-0 SAGE: D = agg @ WL^T + root @ WR^T + bl; LN; ReLU --------------
// A 2-split x B 2-split (h*h -> acc; h*m + m*h -> accL; m*m dropped ~2^-18).
// out may alias agg (same rows: reads complete in-block before writes).
struct FsArgs {
  const float* agg[2];
  const float* root[2];
  const unsigned short *WLh[2], *WLm[2];
  const unsigned short *WRh[2], *WRm[2];
  const float *bl[2], *g[2], *b[2];
  float* out[2];
};
__global__ __launch_bounds__(256, 4) void sage0(FsArgs a) {
  constexpr int NOUT = 128;
  __shared__ __align__(16) unsigned short Ab[4 * kM * kH];  // 32 KB, 4 planes
  float* Cs = (float*)Ab;  // reused post-MFMA: [kM][NOUT+1] fp32
  const int tid = threadIdx.x;
  const int dir = blockIdx.y;
  const size_t row0 = (size_t)blockIdx.x * kM;
  const float* __restrict__ agg = a.agg[dir];
  const float* __restrict__ root = a.root[dir];

  // stage both A matrices, 2-split, swizzled
  for (int c = tid; c < 2048; c += 256) {
    const int mat = c >> 10, cc = c & 1023, r = cc >> 5, j = cc & 31;
    const float4 v = *(const float4*)((mat ? root : agg) + (row0 + r) * kH + j * 4);
    const float* vv = &v.x;
    ushort4v h4, m4;
#pragma unroll
    for (int u = 0; u < 4; ++u) {
      unsigned short th, tm;
      split2(vv[u], th, tm);
      h4[u] = th; m4[u] = tm;
    }
    *(ushort4v*)ab_ptr(Ab, mat * 2 + 0, r, j * 8) = h4;
    *(ushort4v*)ab_ptr(Ab, mat * 2 + 1, r, j * 8) = m4;
  }

  const int lane = tid & 63, w = tid >> 6, q = lane >> 4, ln = lane & 15;
  floatx4 acc[2][2] = {}, accL[2][2] = {};
  const unsigned short* __restrict__ WLh = a.WLh[dir];
  const unsigned short* __restrict__ WLm = a.WLm[dir];
  const unsigned short* __restrict__ WRh = a.WRh[dir];
  const unsigned short* __restrict__ WRm = a.WRm[dir];
  __syncthreads();
#pragma unroll
  for (int kc = 0; kc < 4; ++kc) {
    bf16x8 BL[2][2], BR[2][2];
#pragma unroll
    for (int t = 0; t < 2; ++t) {
      const int off = (w * 32 + t * 16 + ln) * kH + kc * 32 + q * 8;
      BL[0][t] = ldb8(&WLh[off]);
      BL[1][t] = ldb8(&WLm[off]);
      BR[0][t] = ldb8(&WRh[off]);
      BR[1][t] = ldb8(&WRm[off]);
    }
#pragma unroll
    for (int mt = 0; mt < 2; ++mt) {
      const int ro = mt * 16 + ln, cob = kc * 64 + q * 16;
      const bf16x8 a1h = ldb8(ab_ptr(Ab, 0, ro, cob));
      const bf16x8 a1m = ldb8(ab_ptr(Ab, 1, ro, cob));
      const bf16x8 a2h = ldb8(ab_ptr(Ab, 2, ro, cob));
      const bf16x8 a2m = ldb8(ab_ptr(Ab, 3, ro, cob));
#pragma unroll
      for (int t = 0; t < 2; ++t) {
        floatx4 c = acc[mt][t];  // full-scale h*h terms
        c = mfma16(a1h, BL[0][t], c);
        c = mfma16(a2h, BR[0][t], c);
        acc[mt][t] = c;
        floatx4 cl = accL[mt][t];  // low-order terms
        cl = mfma16(a1h, BL[1][t], cl);
        cl = mfma16(a1m, BL[0][t], cl);
        cl = mfma16(a2h, BR[1][t], cl);
        cl = mfma16(a2m, BR[0][t], cl);
        accL[mt][t] = cl;
      }
    }
  }
  __syncthreads();  // done reading Ab; safe to overwrite with Cs
  const float* __restrict__ blv = a.bl[dir];
#pragma unroll
  for (int t = 0; t < 2; ++t) {
    const int colx = (w * 2 + t) * 16 + ln;
    const float bv = blv[colx];
#pragma unroll
    for (int mt = 0; mt < 2; ++mt)
#pragma unroll
      for (int r = 0; r < 4; ++r)
        Cs[(mt * 16 + q * 4 + r) * (NOUT + 1) + colx] =
            (acc[mt][t][r] + accL[mt][t][r]) + bv;
  }
  __syncthreads();
  // Two-pass LayerNorm: 8 threads/row, 16 cols each; ReLU
  const int r = tid >> 3, sub = tid & 7;
  const float* __restrict__ gg = a.g[dir];
  const float* __restrict__ bb = a.b[dir];
  float vals[16], s = 0.f;
#pragma unroll
  for (int j = 0; j < 16; ++j) {
    const float v = Cs[r * (NOUT + 1) + sub * 16 + j];
    vals[j] = v;
    s += v;
  }
#pragma unroll
  for (int o = 1; o < 8; o <<= 1) s += __shfl_xor(s, o, 64);
  const float mean = s * (1.0f / NOUT);
  float s2 = 0.f;
#pragma unroll
  for (int j = 0; j < 16; ++j) {
    const float d = vals[j] - mean;
    s2 += d * d;
  }
#pragma unroll
  for (int o = 1; o < 8; o <<= 1) s2 += __shfl_xor(s2, o, 64);
  const float rstd = rsqrtf(s2 * (1.0f / NOUT) + kEPS);
  float* op = a.out[dir] + (row0 + r) * NOUT + sub * 16;
#pragma unroll
  for (int j = 0; j < 16; j += 4) {
    float4 o4;
    float* oo = &o4.x;
#pragma unroll
    for (int jj = 0; jj < 4; ++jj)
      oo[jj] = fmaxf((vals[j + jj] - mean) * rstd * gg[sub * 16 + j + jj] +
                         bb[sub * 16 + j + jj],
                     0.f);
    *(float4*)&op[j] = o4;
  }
}

// --- layer-1 pre-projection: Z = X @ Wl1 (128 -> 64), no bias ---------------
struct ZArgs {
  const float* src[2];
  const unsigned short *Bh[2], *Bm[2];
  float* out[2];
};
__global__ __launch_bounds__(256, 4) void zproj(ZArgs a) {
  __shared__ __align__(16) unsigned short Ab[2 * kM * kH];  // 16 KB
  const int tid = threadIdx.x, dir = blockIdx.y;
  const size_t row0 = (size_t)blockIdx.x * kM;
  const float* __restrict__ src = a.src[dir];
  for (int c = tid; c < 1024; c += 256) {
    const int r = c >> 5, j = c & 31;
    const float4 v = *(const float4*)&src[(row0 + r) * kH + j * 4];
    const float* vv = &v.x;
    ushort4v h4, m4;
#pragma unroll
    for (int u = 0; u < 4; ++u) {
      unsigned short th, tm;
      split2(vv[u], th, tm);
      h4[u] = th; m4[u] = tm;
    }
    *(ushort4v*)ab_ptr(Ab, 0, r, j * 8) = h4;
    *(ushort4v*)ab_ptr(Ab, 1, r, j * 8) = m4;
  }
  const int lane = tid & 63, w = tid >> 6, q = lane >> 4, ln = lane & 15;
  const unsigned short* __restrict__ Bh = a.Bh[dir];
  const unsigned short* __restrict__ Bm = a.Bm[dir];
  floatx4 acc[2] = {}, accL[2] = {};
  __syncthreads();
#pragma unroll
  for (int kc = 0; kc < 4; ++kc) {
    const int off = (w * 16 + ln) * kH + kc * 32 + q * 8;
    const bf16x8 bh = ldb8(&Bh[off]);
    const bf16x8 bm = ldb8(&Bm[off]);
#pragma unroll
    for (int mt = 0; mt < 2; ++mt) {
      const int ro = mt * 16 + ln, cob = kc * 64 + q * 16;
      const bf16x8 ah = ldb8(ab_ptr(Ab, 0, ro, cob));
      const bf16x8 am = ldb8(ab_ptr(Ab, 1, ro, cob));
      acc[mt] = mfma16(ah, bh, acc[mt]);
      floatx4 cl = accL[mt];
      cl = mfma16(ah, bm, cl);
      cl = mfma16(am, bh, cl);
      accL[mt] = cl;
    }
  }
  float* __restrict__ out = a.out[dir];
  const int col = w * 16 + ln;
#pragma unroll
  for (int mt = 0; mt < 2; ++mt)
#pragma unroll
    for (int r = 0; r < 4; ++r)
      out[(row0 + mt * 16 + q * 4 + r) * kOUT + col] =
          acc[mt][r] + accL[mt][r];
}

// --- layer-1 SAGE finish: D = root @ Wr1 + bl + aggz; LN (no ReLU) ----------
struct S1Args {
  const float* root[2];
  const float* aggz[2];
  const unsigned short *Bh[2], *Bm[2];
  const float *bl[2], *g[2], *b[2];
  float* out[2];
};
__global__ __launch_bounds__(256, 4) void sage1(S1Args a) {
  constexpr int NOUT = kOUT;
  __shared__ __align__(16) unsigned short Ab[2 * kM * kH];  // 16 KB
  float* Cs = (float*)Ab;  // reused post-MFMA: [kM][NOUT+1]
  const int tid = threadIdx.x, dir = blockIdx.y;
  const size_t row0 = (size_t)blockIdx.x * kM;
  const float* __restrict__ root = a.root[dir];
  for (int c = tid; c < 1024; c += 256) {
    const int r = c >> 5, j = c & 31;
    const float4 v = *(const float4*)&root[(row0 + r) * kH + j * 4];
    const float* vv = &v.x;
    ushort4v h4, m4;
#pragma unroll
    for (int u = 0; u < 4; ++u) {
      unsigned short th, tm;
      split2(vv[u], th, tm);
      h4[u] = th; m4[u] = tm;
    }
    *(ushort4v*)ab_ptr(Ab, 0, r, j * 8) = h4;
    *(ushort4v*)ab_ptr(Ab, 1, r, j * 8) = m4;
  }
  const int lane = tid & 63, w = tid >> 6, q = lane >> 4, ln = lane & 15;
  const unsigned short* __restrict__ Bh = a.Bh[dir];
  const unsigned short* __restrict__ Bm = a.Bm[dir];
  floatx4 acc[2] = {}, accL[2] = {};
  __syncthreads();
#pragma unroll
  for (int kc = 0; kc < 4; ++kc) {
    const int off = (w * 16 + ln) * kH + kc * 32 + q * 8;
    const bf16x8 bh = ldb8(&Bh[off]);
    const bf16x8 bm = ldb8(&Bm[off]);
#pragma unroll
    for (int mt = 0; mt < 2; ++mt) {
      const int ro = mt * 16 + ln, cob = kc * 64 + q * 16;
      const bf16x8 ah = ldb8(ab_ptr(Ab, 0, ro, cob));
      const bf16x8 am = ldb8(ab_ptr(Ab, 1, ro, cob));
      acc[mt] = mfma16(ah, bh, acc[mt]);
      floatx4 cl = accL[mt];
      cl = mfma16(ah, bm, cl);
      cl = mfma16(am, bh, cl);
      accL[mt] = cl;
    }
  }
  __syncthreads();  // done reading Ab
  const float* __restrict__ blv = a.bl[dir];
  {
    const int col = w * 16 + ln;
    const float bv = blv[col];
#pragma unroll
    for (int mt = 0; mt < 2; ++mt)
#pragma unroll
      for (int r = 0; r < 4; ++r)
        Cs[(mt * 16 + q * 4 + r) * (NOUT + 1) + col] =
            (acc[mt][r] + accL[mt][r]) + bv;
  }
  __syncthreads();
  // LN over 64 cols: 8 threads/row, 8 cols each; add gathered term from global
  const int r = tid >> 3, sub = tid & 7;
  const float* __restrict__ az = a.aggz[dir];
  const float* __restrict__ gg = a.g[dir];
  const float* __restrict__ bb = a.b[dir];
  const float4 az0 = *(const float4*)&az[(row0 + r) * NOUT + sub * 8];
  const float4 az1 = *(const float4*)&az[(row0 + r) * NOUT + sub * 8 + 4];
  const float* azv = &az0.x;
  float vals[8], s = 0.f;
#pragma unroll
  for (int j = 0; j < 8; ++j) {
    const float v = Cs[r * (NOUT + 1) + sub * 8 + j] +
                    (j < 4 ? (&az0.x)[j] : (&az1.x)[j - 4]);
    vals[j] = v;
    s += v;
  }
  (void)azv;
#pragma unroll
  for (int o = 1; o < 8; o <<= 1) s += __shfl_xor(s, o, 64);
  const float mean = s * (1.0f / NOUT);
  float s2 = 0.f;
#pragma unroll
  for (int j = 0; j < 8; ++j) {
    const float d = vals[j] - mean;
    s2 += d * d;
  }
#pragma unroll
  for (int o = 1; o < 8; o <<= 1) s2 += __shfl_xor(s2, o, 64);
  const float rstd = rsqrtf(s2 * (1.0f / NOUT) + kEPS);
  float* op = a.out[dir] + (row0 + r) * NOUT + sub * 8;
#pragma unroll
  for (int j = 0; j < 8; j += 4) {
    float4 o4;
    float* oo = &o4.x;
#pragma unroll
    for (int jj = 0; jj < 4; ++jj)
      oo[jj] = (vals[j + jj] - mean) * rstd * gg[sub * 8 + j + jj] +
               bb[sub * 8 + j + jj];
    *(float4*)&op[j] = o4;
  }
}

extern "C" void kernel_launch(void* const* d_in, const int* in_sizes, int n_in,
                              void* d_out, int out_size, void* d_ws, size_t ws_size,
                              hipStream_t stream) {
  (void)in_sizes; (void)n_in; (void)out_size; (void)ws_size;
  const float* x_u    = (const float*)d_in[0];
  const float* x_i    = (const float*)d_in[1];
  const int*   e_ui   = (const int*)d_in[2];
  const int*   e_iu   = (const int*)d_in[3];
  const float* Wp_u   = (const float*)d_in[4];
  const float* bp_u   = (const float*)d_in[5];
  const float* Wp_i   = (const float*)d_in[6];
  const float* bp_i   = (const float*)d_in[7];
  const float* Wl0_ui = (const float*)d_in[8];
  const float* bl0_ui = (const float*)d_in[9];
  const float* Wr0_ui = (const float*)d_in[10];
  const float* Wl0_iu = (const float*)d_in[11];
  const float* bl0_iu = (const float*)d_in[12];
  const float* Wr0_iu = (const float*)d_in[13];
  const float* g0_u   = (const float*)d_in[14];
  const float* b0_u   = (const float*)d_in[15];
  const float* g0_i   = (const float*)d_in[16];
  const float* b0_i   = (const float*)d_in[17];
  const float* Wl1_ui = (const float*)d_in[18];
  const float* bl1_ui = (const float*)d_in[19];
  const float* Wr1_ui = (const float*)d_in[20];
  const float* Wl1_iu = (const float*)d_in[21];
  const float* bl1_iu = (const float*)d_in[22];
  const float* Wr1_iu = (const float*)d_in[23];
  const float* g1_u   = (const float*)d_in[24];
  const float* b1_u   = (const float*)d_in[25];
  const float* g1_i   = (const float*)d_in[26];
  const float* b1_i   = (const float*)d_in[27];

  // ---- workspace layout ----
  float* pf = (float*)d_ws;
  const size_t NH = (size_t)kNU * kH;  // 12.8M floats
  float* hu0 = pf;           // projected user feats (later: Zu | Zi)
  float* hi0 = pf + NH;      // projected item feats (later: aggzI | aggzU)
  float* b2  = pf + 2 * NH;  // aggI -> h_i1 (in-place)
  float* b3  = pf + 3 * NH;  // aggU -> h_u1 (in-place)
  float* Zu = hu0;
  float* Zi = hu0 + (size_t)kNU * kOUT;
  float* aggzI = hi0;
  float* aggzU = hi0 + (size_t)kNU * kOUT;
  unsigned short* wh = (unsigned short*)(pf + 4 * NH);  // 131072 ushorts each
  unsigned short* wm = wh + 131072;
  unsigned short* wl = wm + 131072;
  int* pi = (int*)(wl + 131072);
  int* cnt_u = pi; pi += kNU;
  int* cnt_i = pi; pi += kNU;
  int* ptr_u = pi; pi += kNU;
  int* ptr_i = pi; pi += kNU;
  int* cur_u = pi; pi += kNU;
  int* cur_i = pi; pi += kNU;
  int* tot   = pi; pi += 2 * 128;
  int* col_ui = pi; pi += kE;
  int* col_iu = pi; pi += kE;

  // weight sub-offsets (identical layout in h/m/l sets)
  const int oPu = 0, oPi = 12288, o0Lui = 32768, o0Rui = 49152,
            o0Liu = 65536, o0Riu = 81920, o1Lui = 98304, o1Rui = 106496,
            o1Liu = 114688, o1Riu = 122880;

  float* out_u = (float*)d_out;               // h_u2: [100000][64]
  float* out_i = out_u + (size_t)kNU * kOUT;  // h_i2: [100000][64]

  // ---- weight convert/transpose/3-split ----
  WcvtArgs wa;
  const float* wsrc[10] = {Wp_u, Wp_i, Wl0_ui, Wr0_ui, Wl0_iu, Wr0_iu,
                           Wl1_ui, Wr1_ui, Wl1_iu, Wr1_iu};
  const int woff[10] = {oPu, oPi, o0Lui, o0Rui, o0Liu, o0Riu,
                        o1Lui, o1Rui, o1Liu, o1Riu};
  const int wK[10] = {kFU, kFI, kH, kH, kH, kH, kH, kH, kH, kH};
  const int wN[10] = {kH, kH, kH, kH, kH, kH, kOUT, kOUT, kOUT, kOUT};
  for (int i = 0; i < 10; ++i) {
    wa.src[i] = wsrc[i];
    wa.dh[i] = wh + woff[i];
    wa.dm[i] = wm + woff[i];
    wa.dl[i] = wl + woff[i];
    wa.K[i] = wK[i];
    wa.N[i] = wN[i];
  }
  wcvt<<<dim3(80, 10), 256, 0, stream>>>(wa);

  // ---- CSR build (XCD-partitioned) overlapped with projections ----
  zero_int<<<256, 256, 0, stream>>>(cnt_u, 2 * kNU);
  hist_proj<<<8 * kEB + kNBLK, 256, 0, stream>>>(e_ui, e_iu, cnt_i, cnt_u, x_u,
                                                 wh + oPu, wm + oPu, wl + oPu,
                                                 bp_u, hu0);
  scanA<<<dim3(kNCHUNK, 2), 1024, 0, stream>>>(cnt_u, cnt_i, ptr_u, ptr_i, tot);
  scanB<<<2, 128, 0, stream>>>(tot);
  scanC<<<dim3(kNCHUNK, 2), 1024, 0, stream>>>(ptr_u, ptr_i, tot, cur_u, cur_i);
  fill_proj<<<8 * kEB + kNBLK, 256, 0, stream>>>(e_ui, e_iu, cur_i, cur_u,
                                                 col_ui, col_iu, x_i, wh + oPi,
                                                 wm + oPi, wl + oPi, bp_i, hi0);

  // ---- layer 0: gather (both dirs) then SAGE (both dirs) ----
  AggArgs g0;
  g0.src[0] = hu0; g0.ptr[0] = ptr_i; g0.cur[0] = cur_i; g0.col[0] = col_ui;
  g0.out[0] = b2;
  g0.src[1] = hi0; g0.ptr[1] = ptr_u; g0.cur[1] = cur_u; g0.col[1] = col_iu;
  g0.out[1] = b3;
  agg2<kH><<<dim3(kNU / 4, 2), 256, 0, stream>>>(g0);

  FsArgs a0;
  a0.agg[0] = b2; a0.root[0] = hi0;
  a0.WLh[0] = wh + o0Lui; a0.WLm[0] = wm + o0Lui;
  a0.WRh[0] = wh + o0Rui; a0.WRm[0] = wm + o0Rui;
  a0.bl[0] = bl0_ui; a0.g[0] = g0_i; a0.b[0] = b0_i; a0.out[0] = b2;  // h_i1
  a0.agg[1] = b3; a0.root[1] = hu0;
  a0.WLh[1] = wh + o0Liu; a0.WLm[1] = wm + o0Liu;
  a0.WRh[1] = wh + o0Riu; a0.WRm[1] = wm + o0Riu;
  a0.bl[1] = bl0_iu; a0.g[1] = g0_u; a0.b[1] = b0_u; a0.out[1] = b3;  // h_u1
  sage0<<<dim3(kNBLK, 2), 256, 0, stream>>>(a0);

  // ---- layer 1: pre-project Z = h1 @ Wl1 (64-wide), gather Z, finish ----
  ZArgs zp;
  zp.src[0] = b3;  // h_u1 -> Zu (for item aggregation)
  zp.Bh[0] = wh + o1Lui; zp.Bm[0] = wm + o1Lui;
  zp.out[0] = Zu;
  zp.src[1] = b2;  // h_i1 -> Zi (for user aggregation)
  zp.Bh[1] = wh + o1Liu; zp.Bm[1] = wm + o1Liu;
  zp.out[1] = Zi;
  zproj<<<dim3(kNBLK, 2), 256, 0, stream>>>(zp);

  AggArgs g1;
  g1.src[0] = Zu; g1.ptr[0] = ptr_i; g1.cur[0] = cur_i; g1.col[0] = col_ui;
  g1.out[0] = aggzI;
  g1.src[1] = Zi; g1.ptr[1] = ptr_u; g1.cur[1] = cur_u; g1.col[1] = col_iu;
  g1.out[1] = aggzU;
  agg2<kOUT><<<dim3(kNU / 4, 2), 256, 0, stream>>>(g1);

  S1Args s1;
  s1.root[0] = b2; s1.aggz[0] = aggzI;
  s1.Bh[0] = wh + o1Rui; s1.Bm[0] = wm + o1Rui;
  s1.bl[0] = bl1_ui; s1.g[0] = g1_i; s1.b[0] = b1_i; s1.out[0] = out_i;
  s1.root[1] = b3; s1.aggz[1] = aggzU;
  s1.Bh[1] = wh + o1Riu; s1.Bm[1] = wm + o1Riu;
  s1.bl[1] = bl1_iu; s1.g[1] = g1_u; s1.b[1] = b1_u; s1.out[1] = out_u;
  sage1<<<dim3(kNBLK, 2), 256, 0, stream>>>(s1);
}

// Round 5
// 765.393 us; speedup vs baseline: 1.5349x; 1.0122x over previous
//
#include <hip/hip_runtime.h>

typedef __attribute__((ext_vector_type(8))) __bf16 bf16x8;
typedef __attribute__((ext_vector_type(4))) float floatx4;
typedef __attribute__((ext_vector_type(8))) unsigned short ushort8v;
typedef __attribute__((ext_vector_type(4))) unsigned short ushort4v;

namespace {
constexpr int kNU = 100000, kNI = 100000, kE = 600000;
constexpr int kFU = 96, kFI = 160, kH = 128, kOUT = 64;
constexpr float kEPS = 1e-5f;
constexpr int kM = 32;                 // rows per block in MFMA kernels
constexpr int kNCHUNK = 98;            // ceil(100000 / 1024)
constexpr int kNBLK = kNU / kM;        // 3125 row-blocks per node type
constexpr int kEB = (kE + 255) / 256;  // 2344 edge-slices
constexpr int kPART = kNU / 8;         // dst-id range per XCD partition
}

__device__ __forceinline__ unsigned short f2b(float f) {  // fp32 -> bf16 RNE
  unsigned u = __builtin_bit_cast(unsigned, f);
  u += 0x7FFFu + ((u >> 16) & 1u);
  return (unsigned short)(u >> 16);
}
__device__ __forceinline__ float b2f(unsigned short h) {
  return __builtin_bit_cast(float, (unsigned)h << 16);
}
// 3-way bf16 split: v = h + m + l, residual <= ~2^-27 |v|
__device__ __forceinline__ void split3(float v, unsigned short& h,
                                       unsigned short& m, unsigned short& l) {
  h = f2b(v);
  const float r1 = v - b2f(h);   // exact
  m = f2b(r1);
  const float r2 = r1 - b2f(m);  // exact
  l = f2b(r2);
}
// 2-way bf16 split: v = h + m, residual <= ~2^-18 |v|
__device__ __forceinline__ void split2(float v, unsigned short& h,
                                       unsigned short& m) {
  h = f2b(v);
  m = f2b(v - b2f(h));
}
__device__ __forceinline__ bf16x8 ldb8(const unsigned short* p) {
  return __builtin_bit_cast(bf16x8, *(const ushort8v*)p);
}
__device__ __forceinline__ floatx4 mfma16(bf16x8 a, bf16x8 b, floatx4 c) {
  return __builtin_amdgcn_mfma_f32_16x16x32_bf16(a, b, c, 0, 0, 0);
}
// Swizzled LDS accessor: plane stride 8 KB, row stride 256 B, XOR bank swizzle
__device__ __forceinline__ unsigned short* ab_ptr(unsigned short* base,
                                                  int plane, int r, int bo) {
  return (unsigned short*)((char*)base + plane * 8192 + r * 256 +
                           (bo ^ ((r & 7) << 4)));
}

// --- weight convert+transpose+3-split: Wh/Wm/Wl[n][k] = split(W[k][n]) ------
struct WcvtArgs {
  const float* src[10];
  unsigned short* dh[10];
  unsigned short* dm[10];
  unsigned short* dl[10];
  int K[10], N[10];
};
__global__ __launch_bounds__(256) void wcvt(WcvtArgs a) {
  const int m = blockIdx.y;
  const int K = a.K[m], N = a.N[m];
  const int idx = blockIdx.x * 256 + threadIdx.x;
  if (idx < K * N) {
    const int n = idx / K, k = idx - n * K;
    unsigned short h, mm, l;
    split3(a.src[m][(size_t)k * N + n], h, mm, l);
    a.dh[m][idx] = h;
    a.dm[m][idx] = mm;
    a.dl[m][idx] = l;
  }
}

// ---------------- CSR build -------------------------------------------------
__global__ void zero_int(int* __restrict__ p, int n) {
  int i = blockIdx.x * blockDim.x + threadIdx.x;
  const int st = gridDim.x * blockDim.x;
  for (; i < n; i += st) p[i] = 0;
}

// exclusive scan within 1024-chunk; chunk totals to tot[dir*128 + chunk]
__global__ __launch_bounds__(1024) void scanA(const int* __restrict__ cnt_u,
                                              const int* __restrict__ cnt_i,
                                              int* ptr_u, int* ptr_i, int* tot) {
  __shared__ int sh[1024];
  const int dir = blockIdx.y;
  const int* cnt = dir ? cnt_i : cnt_u;
  int* ptr = dir ? ptr_i : ptr_u;
  const int t = threadIdx.x;
  const int i = blockIdx.x * 1024 + t;
  const int v = (i < kNU) ? cnt[i] : 0;
  sh[t] = v;
  __syncthreads();
  for (int o = 1; o < 1024; o <<= 1) {
    const int y = (t >= o) ? sh[t - o] : 0;
    __syncthreads();
    sh[t] += y;
    __syncthreads();
  }
  if (i < kNU) ptr[i] = sh[t] - v;  // exclusive within chunk
  if (t == 1023) tot[dir * 128 + blockIdx.x] = sh[1023];
}

// exclusive scan of the (<=98) chunk totals; one block per direction
__global__ __launch_bounds__(128) void scanB(int* tot) {
  __shared__ int sh[128];
  int* tp = tot + blockIdx.x * 128;
  const int t = threadIdx.x;
  const int v = (t < kNCHUNK) ? tp[t] : 0;
  sh[t] = v;
  __syncthreads();
  for (int o = 1; o < 128; o <<= 1) {
    const int y = (t >= o) ? sh[t - o] : 0;
    __syncthreads();
    sh[t] += y;
    __syncthreads();
  }
  if (t < kNCHUNK) tp[t] = sh[t] - v;  // exclusive
}

__global__ __launch_bounds__(1024) void scanC(int* ptr_u, int* ptr_i,
                                              const int* __restrict__ tot,
                                              int* cur_u, int* cur_i) {
  const int dir = blockIdx.y;
  int* ptr = dir ? ptr_i : ptr_u;
  int* cur = dir ? cur_i : cur_u;
  const int i = blockIdx.x * 1024 + threadIdx.x;
  if (i < kNU) {
    const int v = ptr[i] + tot[dir * 128 + blockIdx.x];
    ptr[i] = v;
    cur[i] = v;
  }
}

// ------- projection body: relu(x @ Wp + b) -> fp32, 3-split bf16 MFMA -------
template <int F>
__device__ __forceinline__ void proj_body(
    const float* __restrict__ x, const unsigned short* __restrict__ Wh,
    const unsigned short* __restrict__ Wm, const unsigned short* __restrict__ Wl,
    const float* __restrict__ bias, float* __restrict__ out, int blk,
    unsigned short* sh) {
  constexpr int AS = F + 8, KC = F / 32;
  unsigned short* Ah = sh;
  unsigned short* Am = sh + kM * AS;
  unsigned short* Al = sh + 2 * kM * AS;
  const int tid = threadIdx.x;
  const size_t row0 = (size_t)blk * kM;
  for (int c = tid; c < kM * (F / 4); c += 256) {
    const int r = c / (F / 4), j = c % (F / 4);
    const float4 v = *(const float4*)&x[(row0 + r) * F + j * 4];
    const float* vv = &v.x;
    ushort4v h4, m4, l4;
#pragma unroll
    for (int u = 0; u < 4; ++u) {
      unsigned short th, tm, tl;
      split3(vv[u], th, tm, tl);
      h4[u] = th; m4[u] = tm; l4[u] = tl;
    }
    *(ushort4v*)&Ah[r * AS + j * 4] = h4;
    *(ushort4v*)&Am[r * AS + j * 4] = m4;
    *(ushort4v*)&Al[r * AS + j * 4] = l4;
  }
  const int lane = tid & 63, w = tid >> 6, q = lane >> 4, ln = lane & 15;
  floatx4 acc[2][2] = {}, accL[2][2] = {};
  __syncthreads();
#pragma unroll
  for (int kc = 0; kc < KC; ++kc) {
    bf16x8 bh[2], bm[2], bl_[2];
#pragma unroll
    for (int t = 0; t < 2; ++t) {
      const int off = (w * 32 + t * 16 + ln) * F + kc * 32 + q * 8;
      bh[t] = ldb8(&Wh[off]);
      bm[t] = ldb8(&Wm[off]);
      bl_[t] = ldb8(&Wl[off]);
    }
#pragma unroll
    for (int mt = 0; mt < 2; ++mt) {
      const int ro = mt * 16 + ln, co = kc * 32 + q * 8;
      const bf16x8 ah = ldb8(&Ah[ro * AS + co]);
      const bf16x8 am = ldb8(&Am[ro * AS + co]);
      const bf16x8 al = ldb8(&Al[ro * AS + co]);
#pragma unroll
      for (int t = 0; t < 2; ++t) {
        acc[mt][t] = mfma16(ah, bh[t], acc[mt][t]);  // full scale
        floatx4 cl = accL[mt][t];                    // low-order
        cl = mfma16(ah, bm[t], cl);
        cl = mfma16(am, bh[t], cl);
        cl = mfma16(ah, bl_[t], cl);
        cl = mfma16(al, bh[t], cl);
        cl = mfma16(am, bm[t], cl);
        accL[mt][t] = cl;
      }
    }
  }
#pragma unroll
  for (int t = 0; t < 2; ++t) {
    const int col = w * 32 + t * 16 + ln;
    const float bv = bias[col];
#pragma unroll
    for (int mt = 0; mt < 2; ++mt)
#pragma unroll
      for (int r = 0; r < 4; ++r)
        out[(row0 + mt * 16 + q * 4 + r) * kH + col] =
            fmaxf((acc[mt][t][r] + accL[mt][t][r]) + bv, 0.f);
  }
}

// --- het kernel 1: XCD-partitioned edge-histogram || user-projection --------
__global__ __launch_bounds__(256, 4) void hist_proj(
    const int* __restrict__ eui, const int* __restrict__ eiu, int* cnt_i,
    int* cnt_u, const float* __restrict__ x,
    const unsigned short* __restrict__ Wh, const unsigned short* __restrict__ Wm,
    const unsigned short* __restrict__ Wl, const float* __restrict__ bias,
    float* __restrict__ out) {
  __shared__ __align__(16) unsigned short sh[3 * kM * (kFU + 8)];
  if (blockIdx.x < 8 * kEB) {
    const int part = blockIdx.x & 7, slice = blockIdx.x >> 3;
    const int e = slice * 256 + threadIdx.x;
    if (e < kE) {
      const int di = eui[kE + e];  // dst item
      if (di / kPART == part) atomicAdd(&cnt_i[di], 1);
      const int du = eiu[kE + e];  // dst user
      if (du / kPART == part) atomicAdd(&cnt_u[du], 1);
    }
  } else {  // user projection (F=96)
    proj_body<kFU>(x, Wh, Wm, Wl, bias, out, blockIdx.x - 8 * kEB, sh);
  }
}

// --- het kernel 2: XCD-partitioned CSR fill || item-projection --------------
__global__ __launch_bounds__(256, 4) void fill_proj(
    const int* __restrict__ eui, const int* __restrict__ eiu, int* cur_i,
    int* cur_u, int* __restrict__ col_ui, int* __restrict__ col_iu,
    const float* __restrict__ x, const unsigned short* __restrict__ Wh,
    const unsigned short* __restrict__ Wm, const unsigned short* __restrict__ Wl,
    const float* __restrict__ bias, float* __restrict__ out) {
  __shared__ __align__(16) unsigned short sh[3 * kM * (kFI + 8)];
  if (blockIdx.x < 8 * kEB) {
    const int part = blockIdx.x & 7, slice = blockIdx.x >> 3;
    const int e = slice * 256 + threadIdx.x;
    if (e < kE) {
      const int di = eui[kE + e];
      if (di / kPART == part) {
        const int p = atomicAdd(&cur_i[di], 1);
        col_ui[p] = eui[e];
      }
      const int du = eiu[kE + e];
      if (du / kPART == part) {
        const int p2 = atomicAdd(&cur_u[du], 1);
        col_iu[p2] = eiu[e];
      }
    }
  } else {  // item projection (F=160)
    proj_body<kFI>(x, Wh, Wm, Wl, bias, out, blockIdx.x - 8 * kEB, sh);
  }
}

// ------- gather-mean (fp32), both dirs, batched-8 loads for MLP -------------
struct AggArgs {
  const float* src[2];
  const int* ptr[2];
  const int* cur[2];
  const int* col[2];
  float* out[2];
};
template <int W>
__global__ __launch_bounds__(256) void agg2(AggArgs a) {
  const int dir = blockIdx.y;
  const int w = threadIdx.x >> 6, lane = threadIdx.x & 63;
  const int row = blockIdx.x * 4 + w;
  const float* __restrict__ feat = a.src[dir];
  const int* __restrict__ col = a.col[dir];
  const int beg = a.ptr[dir][row], end = a.cur[dir][row];
  const float inv = 1.0f / fmaxf((float)(end - beg), 1.0f);
  if (W == 128) {
    float s0 = 0.f, s1 = 0.f;
    for (int e = beg; e < end; e += 8) {
      const int n = end - e;  // uniform across wave
      float2 v[8];
#pragma unroll
      for (int j = 0; j < 8; ++j)
        if (j < n) v[j] = *(const float2*)&feat[(size_t)col[e + j] * 128 + lane * 2];
#pragma unroll
      for (int j = 0; j < 8; ++j)
        if (j < n) { s0 += v[j].x; s1 += v[j].y; }
    }
    float2 o;
    o.x = s0 * inv;
    o.y = s1 * inv;
    *(float2*)&a.out[dir][(size_t)row * 128 + lane * 2] = o;
  } else {  // W == 64
    float s = 0.f;
    for (int e = beg; e < end; e += 8) {
      const int n = end - e;
      float v[8];
#pragma unroll
      for (int j = 0; j < 8; ++j)
        if (j < n) v[j] = feat[(size_t)col[e + j] * 64 + lane];
#pragma unroll
      for (int j = 0; j < 8; ++j)
        if (j < n) s += v[j];
    }
    a.out[dir][(size_t)row * 64 + lane] = s * inv;
  }
}

// --- layer-0 SAGE: D = agg @ WL^T + root @ WR^T + bl; LN; ReLU --------------
// A 2-split x B 2-split. Register-batched staging (8 independent loads in
// flight). out may alias agg (reads complete in-block before writes).
struct FsArgs {
  const float* agg[2];
  const float* root[2];
  const unsigned short *WLh[2], *WLm[2];
  const unsigned short *WRh[2], *WRm[2];
  const float *bl[2], *g[2], *b[2];
  float* out[2];
};
__global__ __launch_bounds__(256, 5) void sage0(FsArgs a) {
  constexpr int NOUT = 128;
  __shared__ __align__(16) unsigned short Ab[4 * kM * kH];  // 32 KB, 4 planes
  float* Cs = (float*)Ab;  // reused post-MFMA: [kM][NOUT+1] fp32
  const int tid = threadIdx.x;
  const int dir = blockIdx.y;
  const size_t row0 = (size_t)blockIdx.x * kM;
  const float* __restrict__ agg = a.agg[dir];
  const float* __restrict__ root = a.root[dir];

  // stage both A matrices, 2-split, swizzled; batch all 8 loads first
  {
    float4 va[8];
#pragma unroll
    for (int k = 0; k < 8; ++k) {
      const int c = tid + k * 256;  // k<4 -> agg half, k>=4 -> root half
      const int cc = c & 1023, r = cc >> 5, j = cc & 31;
      va[k] = *(const float4*)((k < 4 ? agg : root) + (row0 + r) * kH + j * 4);
    }
#pragma unroll
    for (int k = 0; k < 8; ++k) {
      const int c = tid + k * 256;
      const int mat = k >> 2, cc = c & 1023, r = cc >> 5, j = cc & 31;
      const float* vv = &va[k].x;
      ushort4v h4, m4;
#pragma unroll
      for (int u = 0; u < 4; ++u) {
        unsigned short th, tm;
        split2(vv[u], th, tm);
        h4[u] = th; m4[u] = tm;
      }
      *(ushort4v*)ab_ptr(Ab, mat * 2 + 0, r, j * 8) = h4;
      *(ushort4v*)ab_ptr(Ab, mat * 2 + 1, r, j * 8) = m4;
    }
  }

  const int lane = tid & 63, w = tid >> 6, q = lane >> 4, ln = lane & 15;
  floatx4 acc[2][2] = {}, accL[2][2] = {};
  const unsigned short* __restrict__ WLh = a.WLh[dir];
  const unsigned short* __restrict__ WLm = a.WLm[dir];
  const unsigned short* __restrict__ WRh = a.WRh[dir];
  const unsigned short* __restrict__ WRm = a.WRm[dir];
  __syncthreads();
#pragma unroll
  for (int kc = 0; kc < 4; ++kc) {
    bf16x8 BL[2][2], BR[2][2];
#pragma unroll
    for (int t = 0; t < 2; ++t) {
      const int off = (w * 32 + t * 16 + ln) * kH + kc * 32 + q * 8;
      BL[0][t] = ldb8(&WLh[off]);
      BL[1][t] = ldb8(&WLm[off]);
      BR[0][t] = ldb8(&WRh[off]);
      BR[1][t] = ldb8(&WRm[off]);
    }
#pragma unroll
    for (int mt = 0; mt < 2; ++mt) {
      const int ro = mt * 16 + ln, cob = kc * 64 + q * 16;
      const bf16x8 a1h = ldb8(ab_ptr(Ab, 0, ro, cob));
      const bf16x8 a1m = ldb8(ab_ptr(Ab, 1, ro, cob));
      const bf16x8 a2h = ldb8(ab_ptr(Ab, 2, ro, cob));
      const bf16x8 a2m = ldb8(ab_ptr(Ab, 3, ro, cob));
#pragma unroll
      for (int t = 0; t < 2; ++t) {
        floatx4 c = acc[mt][t];  // full-scale h*h terms
        c = mfma16(a1h, BL[0][t], c);
        c = mfma16(a2h, BR[0][t], c);
        acc[mt][t] = c;
        floatx4 cl = accL[mt][t];  // low-order terms
        cl = mfma16(a1h, BL[1][t], cl);
        cl = mfma16(a1m, BL[0][t], cl);
        cl = mfma16(a2h, BR[1][t], cl);
        cl = mfma16(a2m, BR[0][t], cl);
        accL[mt][t] = cl;
      }
    }
  }
  __syncthreads();  // done reading Ab; safe to overwrite with Cs
  const float* __restrict__ blv = a.bl[dir];
#pragma unroll
  for (int t = 0; t < 2; ++t) {
    const int colx = (w * 2 + t) * 16 + ln;
    const float bv = blv[colx];
#pragma unroll
    for (int mt = 0; mt < 2; ++mt)
#pragma unroll
      for (int r = 0; r < 4; ++r)
        Cs[(mt * 16 + q * 4 + r) * (NOUT + 1) + colx] =
            (acc[mt][t][r] + accL[mt][t][r]) + bv;
  }
  __syncthreads();
  // Two-pass LayerNorm: 8 threads/row, 16 cols each; ReLU
  const int r = tid >> 3, sub = tid & 7;
  const float* __restrict__ gg = a.g[dir];
  const float* __restrict__ bb = a.b[dir];
  float vals[16], s = 0.f;
#pragma unroll
  for (int j = 0; j < 16; ++j) {
    const float v = Cs[r * (NOUT + 1) + sub * 16 + j];
    vals[j] = v;
    s += v;
  }
#pragma unroll
  for (int o = 1; o < 8; o <<= 1) s += __shfl_xor(s, o, 64);
  const float mean = s * (1.0f / NOUT);
  float s2 = 0.f;
#pragma unroll
  for (int j = 0; j < 16; ++j) {
    const float d = vals[j] - mean;
    s2 += d * d;
  }
#pragma unroll
  for (int o = 1; o < 8; o <<= 1) s2 += __shfl_xor(s2, o, 64);
  const float rstd = rsqrtf(s2 * (1.0f / NOUT) + kEPS);
  float* op = a.out[dir] + (row0 + r) * NOUT + sub * 16;
#pragma unroll
  for (int j = 0; j < 16; j += 4) {
    float4 o4;
    float* oo = &o4.x;
#pragma unroll
    for (int jj = 0; jj < 4; ++jj)
      oo[jj] = fmaxf((vals[j + jj] - mean) * rstd * gg[sub * 16 + j + jj] +
                         bb[sub * 16 + j + jj],
                     0.f);
    *(float4*)&op[j] = o4;
  }
}

// --- layer-1 pre-projection: Z = X @ Wl1 (128 -> 64), no bias ---------------
struct ZArgs {
  const float* src[2];
  const unsigned short *Bh[2], *Bm[2];
  float* out[2];
};
__global__ __launch_bounds__(256, 6) void zproj(ZArgs a) {
  __shared__ __align__(16) unsigned short Ab[2 * kM * kH];  // 16 KB
  const int tid = threadIdx.x, dir = blockIdx.y;
  const size_t row0 = (size_t)blockIdx.x * kM;
  const float* __restrict__ src = a.src[dir];
  {
    float4 va[4];
#pragma unroll
    for (int k = 0; k < 4; ++k) {
      const int c = tid + k * 256, r = c >> 5, j = c & 31;
      va[k] = *(const float4*)&src[(row0 + r) * kH + j * 4];
    }
#pragma unroll
    for (int k = 0; k < 4; ++k) {
      const int c = tid + k * 256, r = c >> 5, j = c & 31;
      const float* vv = &va[k].x;
      ushort4v h4, m4;
#pragma unroll
      for (int u = 0; u < 4; ++u) {
        unsigned short th, tm;
        split2(vv[u], th, tm);
        h4[u] = th; m4[u] = tm;
      }
      *(ushort4v*)ab_ptr(Ab, 0, r, j * 8) = h4;
      *(ushort4v*)ab_ptr(Ab, 1, r, j * 8) = m4;
    }
  }
  const int lane = tid & 63, w = tid >> 6, q = lane >> 4, ln = lane & 15;
  const unsigned short* __restrict__ Bh = a.Bh[dir];
  const unsigned short* __restrict__ Bm = a.Bm[dir];
  floatx4 acc[2] = {}, accL[2] = {};
  __syncthreads();
#pragma unroll
  for (int kc = 0; kc < 4; ++kc) {
    const int off = (w * 16 + ln) * kH + kc * 32 + q * 8;
    const bf16x8 bh = ldb8(&Bh[off]);
    const bf16x8 bm = ldb8(&Bm[off]);
#pragma unroll
    for (int mt = 0; mt < 2; ++mt) {
      const int ro = mt * 16 + ln, cob = kc * 64 + q * 16;
      const bf16x8 ah = ldb8(ab_ptr(Ab, 0, ro, cob));
      const bf16x8 am = ldb8(ab_ptr(Ab, 1, ro, cob));
      acc[mt] = mfma16(ah, bh, acc[mt]);
      floatx4 cl = accL[mt];
      cl = mfma16(ah, bm, cl);
      cl = mfma16(am, bh, cl);
      accL[mt] = cl;
    }
  }
  float* __restrict__ out = a.out[dir];
  const int col = w * 16 + ln;
#pragma unroll
  for (int mt = 0; mt < 2; ++mt)
#pragma unroll
    for (int r = 0; r < 4; ++r)
      out[(row0 + mt * 16 + q * 4 + r) * kOUT + col] =
          acc[mt][r] + accL[mt][r];
}

// --- layer-1 SAGE finish: D = root @ Wr1 + bl + aggz; LN (no ReLU) ----------
struct S1Args {
  const float* root[2];
  const float* aggz[2];
  const unsigned short *Bh[2], *Bm[2];
  const float *bl[2], *g[2], *b[2];
  float* out[2];
};
__global__ __launch_bounds__(256, 6) void sage1(S1Args a) {
  constexpr int NOUT = kOUT;
  __shared__ __align__(16) unsigned short Ab[2 * kM * kH];  // 16 KB
  float* Cs = (float*)Ab;  // reused post-MFMA: [kM][NOUT+1]
  const int tid = threadIdx.x, dir = blockIdx.y;
  const size_t row0 = (size_t)blockIdx.x * kM;
  const float* __restrict__ root = a.root[dir];
  {
    float4 va[4];
#pragma unroll
    for (int k = 0; k < 4; ++k) {
      const int c = tid + k * 256, r = c >> 5, j = c & 31;
      va[k] = *(const float4*)&root[(row0 + r) * kH + j * 4];
    }
#pragma unroll
    for (int k = 0; k < 4; ++k) {
      const int c = tid + k * 256, r = c >> 5, j = c & 31;
      const float* vv = &va[k].x;
      ushort4v h4, m4;
#pragma unroll
      for (int u = 0; u < 4; ++u) {
        unsigned short th, tm;
        split2(vv[u], th, tm);
        h4[u] = th; m4[u] = tm;
      }
      *(ushort4v*)ab_ptr(Ab, 0, r, j * 8) = h4;
      *(ushort4v*)ab_ptr(Ab, 1, r, j * 8) = m4;
    }
  }
  const int lane = tid & 63, w = tid >> 6, q = lane >> 4, ln = lane & 15;
  const unsigned short* __restrict__ Bh = a.Bh[dir];
  const unsigned short* __restrict__ Bm = a.Bm[dir];
  floatx4 acc[2] = {}, accL[2] = {};
  __syncthreads();
#pragma unroll
  for (int kc = 0; kc < 4; ++kc) {
    const int off = (w * 16 + ln) * kH + kc * 32 + q * 8;
    const bf16x8 bh = ldb8(&Bh[off]);
    const bf16x8 bm = ldb8(&Bm[off]);
#pragma unroll
    for (int mt = 0; mt < 2; ++mt) {
      const int ro = mt * 16 + ln, cob = kc * 64 + q * 16;
      const bf16x8 ah = ldb8(ab_ptr(Ab, 0, ro, cob));
      const bf16x8 am = ldb8(ab_ptr(Ab, 1, ro, cob));
      acc[mt] = mfma16(ah, bh, acc[mt]);
      floatx4 cl = accL[mt];
      cl = mfma16(ah, bm, cl);
      cl = mfma16(am, bh, cl);
      accL[mt] = cl;
    }
  }
  __syncthreads();  // done reading Ab
  const float* __restrict__ blv = a.bl[dir];
  {
    const int col = w * 16 + ln;
    const float bv = blv[col];
#pragma unroll
    for (int mt = 0; mt < 2; ++mt)
#pragma unroll
      for (int r = 0; r < 4; ++r)
        Cs[(mt * 16 + q * 4 + r) * (NOUT + 1) + col] =
            (acc[mt][r] + accL[mt][r]) + bv;
  }
  __syncthreads();
  // LN over 64 cols: 8 threads/row, 8 cols each; add gathered term from global
  const int r = tid >> 3, sub = tid & 7;
  const float* __restrict__ az = a.aggz[dir];
  const float* __restrict__ gg = a.g[dir];
  const float* __restrict__ bb = a.b[dir];
  const float4 az0 = *(const float4*)&az[(row0 + r) * NOUT + sub * 8];
  const float4 az1 = *(const float4*)&az[(row0 + r) * NOUT + sub * 8 + 4];
  float vals[8], s = 0.f;
#pragma unroll
  for (int j = 0; j < 8; ++j) {
    const float v = Cs[r * (NOUT + 1) + sub * 8 + j] +
                    (j < 4 ? (&az0.x)[j] : (&az1.x)[j - 4]);
    vals[j] = v;
    s += v;
  }
#pragma unroll
  for (int o = 1; o < 8; o <<= 1) s += __shfl_xor(s, o, 64);
  const float mean = s * (1.0f / NOUT);
  float s2 = 0.f;
#pragma unroll
  for (int j = 0; j < 8; ++j) {
    const float d = vals[j] - mean;
    s2 += d * d;
  }
#pragma unroll
  for (int o = 1; o < 8; o <<= 1) s2 += __shfl_xor(s2, o, 64);
  const float rstd = rsqrtf(s2 * (1.0f / NOUT) + kEPS);
  float* op = a.out[dir] + (row0 + r) * NOUT + sub * 8;
#pragma unroll
  for (int j = 0; j < 8; j += 4) {
    float4 o4;
    float* oo = &o4.x;
#pragma unroll
    for (int jj = 0; jj < 4; ++jj)
      oo[jj] = (vals[j + jj] - mean) * rstd * gg[sub * 8 + j + jj] +
               bb[sub * 8 + j + jj];
    *(float4*)&op[j] = o4;
  }
}

extern "C" void kernel_launch(void* const* d_in, const int* in_sizes, int n_in,
                              void* d_out, int out_size, void* d_ws, size_t ws_size,
                              hipStream_t stream) {
  (void)in_sizes; (void)n_in; (void)out_size; (void)ws_size;
  const float* x_u    = (const float*)d_in[0];
  const float* x_i    = (const float*)d_in[1];
  const int*   e_ui   = (const int*)d_in[2];
  const int*   e_iu   = (const int*)d_in[3];
  const float* Wp_u   = (const float*)d_in[4];
  const float* bp_u   = (const float*)d_in[5];
  const float* Wp_i   = (const float*)d_in[6];
  const float* bp_i   = (const float*)d_in[7];
  const float* Wl0_ui = (const float*)d_in[8];
  const float* bl0_ui = (const float*)d_in[9];
  const float* Wr0_ui = (const float*)d_in[10];
  const float* Wl0_iu = (const float*)d_in[11];
  const float* bl0_iu = (const float*)d_in[12];
  const float* Wr0_iu = (const float*)d_in[13];
  const float* g0_u   = (const float*)d_in[14];
  const float* b0_u   = (const float*)d_in[15];
  const float* g0_i   = (const float*)d_in[16];
  const float* b0_i   = (const float*)d_in[17];
  const float* Wl1_ui = (const float*)d_in[18];
  const float* bl1_ui = (const float*)d_in[19];
  const float* Wr1_ui = (const float*)d_in[20];
  const float* Wl1_iu = (const float*)d_in[21];
  const float* bl1_iu = (const float*)d_in[22];
  const float* Wr1_iu = (const float*)d_in[23];
  const float* g1_u   = (const float*)d_in[24];
  const float* b1_u   = (const float*)d_in[25];
  const float* g1_i   = (const float*)d_in[26];
  const float* b1_i   = (const float*)d_in[27];

  // ---- workspace layout ----
  float* pf = (float*)d_ws;
  const size_t NH = (size_t)kNU * kH;  // 12.8M floats
  float* hu0 = pf;           // projected user feats (later: Zu | Zi)
  float* hi0 = pf + NH;      // projected item feats (later: aggzI | aggzU)
  float* b2  = pf + 2 * NH;  // aggI -> h_i1 (in-place)
  float* b3  = pf + 3 * NH;  // aggU -> h_u1 (in-place)
  float* Zu = hu0;
  float* Zi = hu0 + (size_t)kNU * kOUT;
  float* aggzI = hi0;
  float* aggzU = hi0 + (size_t)kNU * kOUT;
  unsigned short* wh = (unsigned short*)(pf + 4 * NH);  // 131072 ushorts each
  unsigned short* wm = wh + 131072;
  unsigned short* wl = wm + 131072;
  int* pi = (int*)(wl + 131072);
  int* cnt_u = pi; pi += kNU;
  int* cnt_i = pi; pi += kNU;
  int* ptr_u = pi; pi += kNU;
  int* ptr_i = pi; pi += kNU;
  int* cur_u = pi; pi += kNU;
  int* cur_i = pi; pi += kNU;
  int* tot   = pi; pi += 2 * 128;
  int* col_ui = pi; pi += kE;
  int* col_iu = pi; pi += kE;

  // weight sub-offsets (identical layout in h/m/l sets)
  const int oPu = 0, oPi = 12288, o0Lui = 32768, o0Rui = 49152,
            o0Liu = 65536, o0Riu = 81920, o1Lui = 98304, o1Rui = 106496,
            o1Liu = 114688, o1Riu = 122880;

  float* out_u = (float*)d_out;               // h_u2: [100000][64]
  float* out_i = out_u + (size_t)kNU * kOUT;  // h_i2: [100000][64]

  // ---- weight convert/transpose/3-split ----
  WcvtArgs wa;
  const float* wsrc[10] = {Wp_u, Wp_i, Wl0_ui, Wr0_ui, Wl0_iu, Wr0_iu,
                           Wl1_ui, Wr1_ui, Wl1_iu, Wr1_iu};
  const int woff[10] = {oPu, oPi, o0Lui, o0Rui, o0Liu, o0Riu,
                        o1Lui, o1Rui, o1Liu, o1Riu};
  const int wK[10] = {kFU, kFI, kH, kH, kH, kH, kH, kH, kH, kH};
  const int wN[10] = {kH, kH, kH, kH, kH, kH, kOUT, kOUT, kOUT, kOUT};
  for (int i = 0; i < 10; ++i) {
    wa.src[i] = wsrc[i];
    wa.dh[i] = wh + woff[i];
    wa.dm[i] = wm + woff[i];
    wa.dl[i] = wl + woff[i];
    wa.K[i] = wK[i];
    wa.N[i] = wN[i];
  }
  wcvt<<<dim3(80, 10), 256, 0, stream>>>(wa);

  // ---- CSR build (XCD-partitioned) overlapped with projections ----
  zero_int<<<256, 256, 0, stream>>>(cnt_u, 2 * kNU);
  hist_proj<<<8 * kEB + kNBLK, 256, 0, stream>>>(e_ui, e_iu, cnt_i, cnt_u, x_u,
                                                 wh + oPu, wm + oPu, wl + oPu,
                                                 bp_u, hu0);
  scanA<<<dim3(kNCHUNK, 2), 1024, 0, stream>>>(cnt_u, cnt_i, ptr_u, ptr_i, tot);
  scanB<<<2, 128, 0, stream>>>(tot);
  scanC<<<dim3(kNCHUNK, 2), 1024, 0, stream>>>(ptr_u, ptr_i, tot, cur_u, cur_i);
  fill_proj<<<8 * kEB + kNBLK, 256, 0, stream>>>(e_ui, e_iu, cur_i, cur_u,
                                                 col_ui, col_iu, x_i, wh + oPi,
                                                 wm + oPi, wl + oPi, bp_i, hi0);

  // ---- layer 0: gather (both dirs) then SAGE (both dirs) ----
  AggArgs g0;
  g0.src[0] = hu0; g0.ptr[0] = ptr_i; g0.cur[0] = cur_i; g0.col[0] = col_ui;
  g0.out[0] = b2;
  g0.src[1] = hi0; g0.ptr[1] = ptr_u; g0.cur[1] = cur_u; g0.col[1] = col_iu;
  g0.out[1] = b3;
  agg2<kH><<<dim3(kNU / 4, 2), 256, 0, stream>>>(g0);

  FsArgs a0;
  a0.agg[0] = b2; a0.root[0] = hi0;
  a0.WLh[0] = wh + o0Lui; a0.WLm[0] = wm + o0Lui;
  a0.WRh[0] = wh + o0Rui; a0.WRm[0] = wm + o0Rui;
  a0.bl[0] = bl0_ui; a0.g[0] = g0_i; a0.b[0] = b0_i; a0.out[0] = b2;  // h_i1
  a0.agg[1] = b3; a0.root[1] = hu0;
  a0.WLh[1] = wh + o0Liu; a0.WLm[1] = wm + o0Liu;
  a0.WRh[1] = wh + o0Riu; a0.WRm[1] = wm + o0Riu;
  a0.bl[1] = bl0_iu; a0.g[1] = g0_u; a0.b[1] = b0_u; a0.out[1] = b3;  // h_u1
  sage0<<<dim3(kNBLK, 2), 256, 0, stream>>>(a0);

  // ---- layer 1: pre-project Z = h1 @ Wl1 (64-wide), gather Z, finish ----
  ZArgs zp;
  zp.src[0] = b3;  // h_u1 -> Zu (for item aggregation)
  zp.Bh[0] = wh + o1Lui; zp.Bm[0] = wm + o1Lui;
  zp.out[0] = Zu;
  zp.src[1] = b2;  // h_i1 -> Zi (for user aggregation)
  zp.Bh[1] = wh + o1Liu; zp.Bm[1] = wm + o1Liu;
  zp.out[1] = Zi;
  zproj<<<dim3(kNBLK, 2), 256, 0, stream>>>(zp);

  AggArgs g1;
  g1.src[0] = Zu; g1.ptr[0] = ptr_i; g1.cur[0] = cur_i; g1.col[0] = col_ui;
  g1.out[0] = aggzI;
  g1.src[1] = Zi; g1.ptr[1] = ptr_u; g1.cur[1] = cur_u; g1.col[1] = col_iu;
  g1.out[1] = aggzU;
  agg2<kOUT><<<dim3(kNU / 4, 2), 256, 0, stream>>>(g1);

  S1Args s1;
  s1.root[0] = b2; s1.aggz[0] = aggzI;
  s1.Bh[0] = wh + o1Rui; s1.Bm[0] = wm + o1Rui;
  s1.bl[0] = bl1_ui; s1.g[0] = g1_i; s1.b[0] = b1_i; s1.out[0] = out_i;
  s1.root[1] = b3; s1.aggz[1] = aggzU;
  s1.Bh[1] = wh + o1Riu; s1.Bm[1] = wm + o1Riu;
  s1.bl[1] = bl1_iu; s1.g[1] = g1_u; s1.b[1] = b1_u; s1.out[1] = out_u;
  sage1<<<dim3(kNBLK, 2), 256, 0, stream>>>(s1);
}

// Round 7
// 712.903 us; speedup vs baseline: 1.6479x; 1.0736x over previous
//
#include <hip/hip_runtime.h>

typedef __attribute__((ext_vector_type(8))) __bf16 bf16x8;
typedef __attribute__((ext_vector_type(4))) float floatx4;
typedef __attribute__((ext_vector_type(8))) unsigned short ushort8v;
typedef __attribute__((ext_vector_type(4))) unsigned short ushort4v;

namespace {
constexpr int kNU = 100000, kNI = 100000, kE = 600000;
constexpr int kFU = 96, kFI = 160, kH = 128, kOUT = 64;
constexpr float kEPS = 1e-5f;
constexpr int kM = 32;                 // rows per block in MFMA kernels
constexpr int kNCHUNK = 98;            // ceil(100000 / 1024)
constexpr int kNBLK = kNU / kM;        // 3125 row-blocks per node type
constexpr int kEB = (kE + 255) / 256;  // 2344 edge-slices
constexpr int kPART = kNU / 8;         // dst-id range per XCD partition
}

__device__ __forceinline__ unsigned short f2b(float f) {  // fp32 -> bf16 RNE
  unsigned u = __builtin_bit_cast(unsigned, f);
  u += 0x7FFFu + ((u >> 16) & 1u);
  return (unsigned short)(u >> 16);
}
__device__ __forceinline__ float b2f(unsigned short h) {
  return __builtin_bit_cast(float, (unsigned)h << 16);
}
// 3-way bf16 split: v = h + m + l, residual <= ~2^-27 |v|
__device__ __forceinline__ void split3(float v, unsigned short& h,
                                       unsigned short& m, unsigned short& l) {
  h = f2b(v);
  const float r1 = v - b2f(h);   // exact
  m = f2b(r1);
  const float r2 = r1 - b2f(m);  // exact
  l = f2b(r2);
}
// 2-way bf16 split: v = h + m, residual <= ~2^-18 |v|
__device__ __forceinline__ void split2(float v, unsigned short& h,
                                       unsigned short& m) {
  h = f2b(v);
  m = f2b(v - b2f(h));
}
__device__ __forceinline__ bf16x8 ldb8(const unsigned short* p) {
  return __builtin_bit_cast(bf16x8, *(const ushort8v*)p);
}
__device__ __forceinline__ floatx4 mfma16(bf16x8 a, bf16x8 b, floatx4 c) {
  return __builtin_amdgcn_mfma_f32_16x16x32_bf16(a, b, c, 0, 0, 0);
}
// Swizzled LDS accessor: plane stride 8 KB, row stride 256 B, XOR bank swizzle
__device__ __forceinline__ unsigned short* ab_ptr(unsigned short* base,
                                                  int plane, int r, int bo) {
  return (unsigned short*)((char*)base + plane * 8192 + r * 256 +
                           (bo ^ ((r & 7) << 4)));
}

// --- weight convert+transpose+3-split: Wh/Wm/Wl[n][k] = split(W[k][n]) ------
struct WcvtArgs {
  const float* src[10];
  unsigned short* dh[10];
  unsigned short* dm[10];
  unsigned short* dl[10];
  int K[10], N[10];
};
__global__ __launch_bounds__(256) void wcvt(WcvtArgs a) {
  const int m = blockIdx.y;
  const int K = a.K[m], N = a.N[m];
  const int idx = blockIdx.x * 256 + threadIdx.x;
  if (idx < K * N) {
    const int n = idx / K, k = idx - n * K;
    unsigned short h, mm, l;
    split3(a.src[m][(size_t)k * N + n], h, mm, l);
    a.dh[m][idx] = h;
    a.dm[m][idx] = mm;
    a.dl[m][idx] = l;
  }
}

// ---------------- CSR build -------------------------------------------------
__global__ void zero_int(int* __restrict__ p, int n) {
  int i = blockIdx.x * blockDim.x + threadIdx.x;
  const int st = gridDim.x * blockDim.x;
  for (; i < n; i += st) p[i] = 0;
}

// exclusive scan within 1024-chunk; chunk totals to tot[dir*128 + chunk]
__global__ __launch_bounds__(1024) void scanA(const int* __restrict__ cnt_u,
                                              const int* __restrict__ cnt_i,
                                              int* ptr_u, int* ptr_i, int* tot) {
  __shared__ int sh[1024];
  const int dir = blockIdx.y;
  const int* cnt = dir ? cnt_i : cnt_u;
  int* ptr = dir ? ptr_i : ptr_u;
  const int t = threadIdx.x;
  const int i = blockIdx.x * 1024 + t;
  const int v = (i < kNU) ? cnt[i] : 0;
  sh[t] = v;
  __syncthreads();
  for (int o = 1; o < 1024; o <<= 1) {
    const int y = (t >= o) ? sh[t - o] : 0;
    __syncthreads();
    sh[t] += y;
    __syncthreads();
  }
  if (i < kNU) ptr[i] = sh[t] - v;  // exclusive within chunk
  if (t == 1023) tot[dir * 128 + blockIdx.x] = sh[1023];
}

// exclusive scan of the (<=98) chunk totals; one block per direction
__global__ __launch_bounds__(128) void scanB(int* tot) {
  __shared__ int sh[128];
  int* tp = tot + blockIdx.x * 128;
  const int t = threadIdx.x;
  const int v = (t < kNCHUNK) ? tp[t] : 0;
  sh[t] = v;
  __syncthreads();
  for (int o = 1; o < 128; o <<= 1) {
    const int y = (t >= o) ? sh[t - o] : 0;
    __syncthreads();
    sh[t] += y;
    __syncthreads();
  }
  if (t < kNCHUNK) tp[t] = sh[t] - v;  // exclusive
}

__global__ __launch_bounds__(1024) void scanC(int* ptr_u, int* ptr_i,
                                              const int* __restrict__ tot,
                                              int* cur_u, int* cur_i) {
  const int dir = blockIdx.y;
  int* ptr = dir ? ptr_i : ptr_u;
  int* cur = dir ? cur_i : cur_u;
  const int i = blockIdx.x * 1024 + threadIdx.x;
  if (i < kNU) {
    const int v = ptr[i] + tot[dir * 128 + blockIdx.x];
    ptr[i] = v;
    cur[i] = v;
  }
}

// ------- projection body: relu(x @ Wp + b) -> fp32, 3-split bf16 MFMA -------
template <int F>
__device__ __forceinline__ void proj_body(
    const float* __restrict__ x, const unsigned short* __restrict__ Wh,
    const unsigned short* __restrict__ Wm, const unsigned short* __restrict__ Wl,
    const float* __restrict__ bias, float* __restrict__ out, int blk,
    unsigned short* sh) {
  constexpr int AS = F + 8, KC = F / 32;
  unsigned short* Ah = sh;
  unsigned short* Am = sh + kM * AS;
  unsigned short* Al = sh + 2 * kM * AS;
  const int tid = threadIdx.x;
  const size_t row0 = (size_t)blk * kM;
  for (int c = tid; c < kM * (F / 4); c += 256) {
    const int r = c / (F / 4), j = c % (F / 4);
    const float4 v = *(const float4*)&x[(row0 + r) * F + j * 4];
    const float* vv = &v.x;
    ushort4v h4, m4, l4;
#pragma unroll
    for (int u = 0; u < 4; ++u) {
      unsigned short th, tm, tl;
      split3(vv[u], th, tm, tl);
      h4[u] = th; m4[u] = tm; l4[u] = tl;
    }
    *(ushort4v*)&Ah[r * AS + j * 4] = h4;
    *(ushort4v*)&Am[r * AS + j * 4] = m4;
    *(ushort4v*)&Al[r * AS + j * 4] = l4;
  }
  const int lane = tid & 63, w = tid >> 6, q = lane >> 4, ln = lane & 15;
  floatx4 acc[2][2] = {}, accL[2][2] = {};
  __syncthreads();
#pragma unroll
  for (int kc = 0; kc < KC; ++kc) {
    bf16x8 bh[2], bm[2], bl_[2];
#pragma unroll
    for (int t = 0; t < 2; ++t) {
      const int off = (w * 32 + t * 16 + ln) * F + kc * 32 + q * 8;
      bh[t] = ldb8(&Wh[off]);
      bm[t] = ldb8(&Wm[off]);
      bl_[t] = ldb8(&Wl[off]);
    }
#pragma unroll
    for (int mt = 0; mt < 2; ++mt) {
      const int ro = mt * 16 + ln, co = kc * 32 + q * 8;
      const bf16x8 ah = ldb8(&Ah[ro * AS + co]);
      const bf16x8 am = ldb8(&Am[ro * AS + co]);
      const bf16x8 al = ldb8(&Al[ro * AS + co]);
#pragma unroll
      for (int t = 0; t < 2; ++t) {
        acc[mt][t] = mfma16(ah, bh[t], acc[mt][t]);  // full scale
        floatx4 cl = accL[mt][t];                    // low-order
        cl = mfma16(ah, bm[t], cl);
        cl = mfma16(am, bh[t], cl);
        cl = mfma16(ah, bl_[t], cl);
        cl = mfma16(al, bh[t], cl);
        cl = mfma16(am, bm[t], cl);
        accL[mt][t] = cl;
      }
    }
  }
#pragma unroll
  for (int t = 0; t < 2; ++t) {
    const int col = w * 32 + t * 16 + ln;
    const float bv = bias[col];
#pragma unroll
    for (int mt = 0; mt < 2; ++mt)
#pragma unroll
      for (int r = 0; r < 4; ++r)
        out[(row0 + mt * 16 + q * 4 + r) * kH + col] =
            fmaxf((acc[mt][t][r] + accL[mt][t][r]) + bv, 0.f);
  }
}

// --- het kernel 1: XCD-partitioned edge-histogram || user-projection --------
__global__ __launch_bounds__(256, 4) void hist_proj(
    const int* __restrict__ eui, const int* __restrict__ eiu, int* cnt_i,
    int* cnt_u, const float* __restrict__ x,
    const unsigned short* __restrict__ Wh, const unsigned short* __restrict__ Wm,
    const unsigned short* __restrict__ Wl, const float* __restrict__ bias,
    float* __restrict__ out) {
  __shared__ __align__(16) unsigned short sh[3 * kM * (kFU + 8)];
  if (blockIdx.x < 8 * kEB) {
    const int part = blockIdx.x & 7, slice = blockIdx.x >> 3;
    const int e = slice * 256 + threadIdx.x;
    if (e < kE) {
      const int di = eui[kE + e];  // dst item
      if (di / kPART == part) atomicAdd(&cnt_i[di], 1);
      const int du = eiu[kE + e];  // dst user
      if (du / kPART == part) atomicAdd(&cnt_u[du], 1);
    }
  } else {  // user projection (F=96)
    proj_body<kFU>(x, Wh, Wm, Wl, bias, out, blockIdx.x - 8 * kEB, sh);
  }
}

// --- het kernel 2: XCD-partitioned CSR fill || item-projection --------------
__global__ __launch_bounds__(256, 4) void fill_proj(
    const int* __restrict__ eui, const int* __restrict__ eiu, int* cur_i,
    int* cur_u, int* __restrict__ col_ui, int* __restrict__ col_iu,
    const float* __restrict__ x, const unsigned short* __restrict__ Wh,
    const unsigned short* __restrict__ Wm, const unsigned short* __restrict__ Wl,
    const float* __restrict__ bias, float* __restrict__ out) {
  __shared__ __align__(16) unsigned short sh[3 * kM * (kFI + 8)];
  if (blockIdx.x < 8 * kEB) {
    const int part = blockIdx.x & 7, slice = blockIdx.x >> 3;
    const int e = slice * 256 + threadIdx.x;
    if (e < kE) {
      const int di = eui[kE + e];
      if (di / kPART == part) {
        const int p = atomicAdd(&cur_i[di], 1);
        col_ui[p] = eui[e];
      }
      const int du = eiu[kE + e];
      if (du / kPART == part) {
        const int p2 = atomicAdd(&cur_u[du], 1);
        col_iu[p2] = eiu[e];
      }
    }
  } else {  // item projection (F=160)
    proj_body<kFI>(x, Wh, Wm, Wl, bias, out, blockIdx.x - 8 * kEB, sh);
  }
}

// ------- gather-mean (fp32), both dirs; fenced 8-deep load batches ----------
struct AggArgs {
  const float* src[2];
  const int* ptr[2];
  const int* cur[2];
  const int* col[2];
  float* out[2];
};
template <int W>
__global__ __launch_bounds__(256) void agg2(AggArgs a) {
  const int dir = blockIdx.y;
  const int w = threadIdx.x >> 6, lane = threadIdx.x & 63;
  const int row = blockIdx.x * 4 + w;
  const float* __restrict__ feat = a.src[dir];
  const int* __restrict__ col = a.col[dir];
  const int beg = a.ptr[dir][row], end = a.cur[dir][row];
  const float inv = 1.0f / fmaxf((float)(end - beg), 1.0f);
  if (W == 128) {
    float s0 = 0.f, s1 = 0.f;
    for (int e = beg; e < end; e += 8) {
      const int n = end - e;  // uniform across wave
      int cidx[8];
#pragma unroll
      for (int j = 0; j < 8; ++j) cidx[j] = col[(j < n) ? (e + j) : e];
      __builtin_amdgcn_sched_barrier(0);
      float2 v[8];
#pragma unroll
      for (int j = 0; j < 8; ++j)
        if (j < n) v[j] = *(const float2*)&feat[(size_t)cidx[j] * 128 + lane * 2];
      __builtin_amdgcn_sched_barrier(0);
#pragma unroll
      for (int j = 0; j < 8; ++j)
        if (j < n) { s0 += v[j].x; s1 += v[j].y; }
    }
    float2 o;
    o.x = s0 * inv;
    o.y = s1 * inv;
    *(float2*)&a.out[dir][(size_t)row * 128 + lane * 2] = o;
  } else {  // W == 64
    float s = 0.f;
    for (int e = beg; e < end; e += 8) {
      const int n = end - e;
      int cidx[8];
#pragma unroll
      for (int j = 0; j < 8; ++j) cidx[j] = col[(j < n) ? (e + j) : e];
      __builtin_amdgcn_sched_barrier(0);
      float v[8];
#pragma unroll
      for (int j = 0; j < 8; ++j)
        if (j < n) v[j] = feat[(size_t)cidx[j] * 64 + lane];
      __builtin_amdgcn_sched_barrier(0);
#pragma unroll
      for (int j = 0; j < 8; ++j)
        if (j < n) s += v[j];
    }
    a.out[dir][(size_t)row * 64 + lane] = s * inv;
  }
}

// --- layer-0 SAGE: D = agg @ WL^T + root @ WR^T + bl; LN; ReLU --------------
// A 2-split x B 2-split. Fenced staging batch + register-double-buffered
// weight prefetch (loads hide under MFMA). out may alias agg.
struct FsArgs {
  const float* agg[2];
  const float* root[2];
  const unsigned short *WLh[2], *WLm[2];
  const unsigned short *WRh[2], *WRm[2];
  const float *bl[2], *g[2], *b[2];
  float* out[2];
};

#define LOADW_S0(B, KC)                                                  \
  {                                                                      \
    const int o0_ = (w * 32 + 0 * 16 + ln) * kH + (KC) * 32 + q * 8;     \
    const int o1_ = (w * 32 + 1 * 16 + ln) * kH + (KC) * 32 + q * 8;     \
    BLh[B][0] = ldb8(&WLh[o0_]); BLh[B][1] = ldb8(&WLh[o1_]);            \
    BLm[B][0] = ldb8(&WLm[o0_]); BLm[B][1] = ldb8(&WLm[o1_]);            \
    BRh[B][0] = ldb8(&WRh[o0_]); BRh[B][1] = ldb8(&WRh[o1_]);            \
    BRm[B][0] = ldb8(&WRm[o0_]); BRm[B][1] = ldb8(&WRm[o1_]);            \
  }

__global__ __launch_bounds__(256, 4) void sage0(FsArgs a) {
  constexpr int NOUT = 128;
  __shared__ __align__(16) unsigned short Ab[4 * kM * kH];  // 32 KB, 4 planes
  float* Cs = (float*)Ab;  // reused post-MFMA: [kM][NOUT+1] fp32
  const int tid = threadIdx.x;
  const int dir = blockIdx.y;
  const size_t row0 = (size_t)blockIdx.x * kM;
  const float* __restrict__ agg = a.agg[dir];
  const float* __restrict__ root = a.root[dir];
  const unsigned short* __restrict__ WLh = a.WLh[dir];
  const unsigned short* __restrict__ WLm = a.WLm[dir];
  const unsigned short* __restrict__ WRh = a.WRh[dir];
  const unsigned short* __restrict__ WRm = a.WRm[dir];
  const int lane = tid & 63, w = tid >> 6, q = lane >> 4, ln = lane & 15;

  // Phase 1: issue ALL staging loads (8x float4) + kc=0 weight loads, then
  // fence so the compiler cannot re-serialize them into load->use chains.
  float4 va[8];
#pragma unroll
  for (int k = 0; k < 8; ++k) {
    const int c = tid + (k & 3) * 256;  // k<4: agg half, k>=4: root half
    const int r = c >> 5, j = c & 31;
    va[k] = *(const float4*)((k < 4 ? agg : root) + (row0 + r) * kH + j * 4);
  }
  bf16x8 BLh[2][2], BLm[2][2], BRh[2][2], BRm[2][2];
  LOADW_S0(0, 0);
  __builtin_amdgcn_sched_barrier(0);

  // Phase 2: convert + LDS store (weight loads still in flight above).
#pragma unroll
  for (int k = 0; k < 8; ++k) {
    const int c = tid + (k & 3) * 256;
    const int mat = k >> 2, r = c >> 5, j = c & 31;
    const float* vv = &va[k].x;
    ushort4v h4, m4;
#pragma unroll
    for (int u = 0; u < 4; ++u) {
      unsigned short th, tm;
      split2(vv[u], th, tm);
      h4[u] = th; m4[u] = tm;
    }
    *(ushort4v*)ab_ptr(Ab, mat * 2 + 0, r, j * 8) = h4;
    *(ushort4v*)ab_ptr(Ab, mat * 2 + 1, r, j * 8) = m4;
  }

  floatx4 acc[2][2] = {}, accL[2][2] = {};
  __syncthreads();
#pragma unroll
  for (int kc = 0; kc < 4; ++kc) {
    if (kc < 3) LOADW_S0((kc + 1) & 1, kc + 1);  // prefetch next kc
    __builtin_amdgcn_sched_barrier(0);           // pin: issue before MFMAs
#pragma unroll
    for (int mt = 0; mt < 2; ++mt) {
      const int ro = mt * 16 + ln, cob = kc * 64 + q * 16;
      const bf16x8 a1h = ldb8(ab_ptr(Ab, 0, ro, cob));
      const bf16x8 a1m = ldb8(ab_ptr(Ab, 1, ro, cob));
      const bf16x8 a2h = ldb8(ab_ptr(Ab, 2, ro, cob));
      const bf16x8 a2m = ldb8(ab_ptr(Ab, 3, ro, cob));
#pragma unroll
      for (int t = 0; t < 2; ++t) {
        floatx4 c = acc[mt][t];  // full-scale h*h terms
        c = mfma16(a1h, BLh[kc & 1][t], c);
        c = mfma16(a2h, BRh[kc & 1][t], c);
        acc[mt][t] = c;
        floatx4 cl = accL[mt][t];  // low-order terms
        cl = mfma16(a1h, BLm[kc & 1][t], cl);
        cl = mfma16(a1m, BLh[kc & 1][t], cl);
        cl = mfma16(a2h, BRm[kc & 1][t], cl);
        cl = mfma16(a2m, BRh[kc & 1][t], cl);
        accL[mt][t] = cl;
      }
    }
  }
  __syncthreads();  // done reading Ab; safe to overwrite with Cs
  const float* __restrict__ blv = a.bl[dir];
#pragma unroll
  for (int t = 0; t < 2; ++t) {
    const int colx = (w * 2 + t) * 16 + ln;
    const float bv = blv[colx];
#pragma unroll
    for (int mt = 0; mt < 2; ++mt)
#pragma unroll
      for (int r = 0; r < 4; ++r)
        Cs[(mt * 16 + q * 4 + r) * (NOUT + 1) + colx] =
            (acc[mt][t][r] + accL[mt][t][r]) + bv;
  }
  __syncthreads();
  // Two-pass LayerNorm: 8 threads/row, 16 cols each; ReLU
  const int r = tid >> 3, sub = tid & 7;
  const float* __restrict__ gg = a.g[dir];
  const float* __restrict__ bb = a.b[dir];
  float vals[16], s = 0.f;
#pragma unroll
  for (int j = 0; j < 16; ++j) {
    const float v = Cs[r * (NOUT + 1) + sub * 16 + j];
    vals[j] = v;
    s += v;
  }
#pragma unroll
  for (int o = 1; o < 8; o <<= 1) s += __shfl_xor(s, o, 64);
  const float mean = s * (1.0f / NOUT);
  float s2 = 0.f;
#pragma unroll
  for (int j = 0; j < 16; ++j) {
    const float d = vals[j] - mean;
    s2 += d * d;
  }
#pragma unroll
  for (int o = 1; o < 8; o <<= 1) s2 += __shfl_xor(s2, o, 64);
  const float rstd = rsqrtf(s2 * (1.0f / NOUT) + kEPS);
  float* op = a.out[dir] + (row0 + r) * NOUT + sub * 16;
#pragma unroll
  for (int j = 0; j < 16; j += 4) {
    float4 o4;
    float* oo = &o4.x;
#pragma unroll
    for (int jj = 0; jj < 4; ++jj)
      oo[jj] = fmaxf((vals[j + jj] - mean) * rstd * gg[sub * 16 + j + jj] +
                         bb[sub * 16 + j + jj],
                     0.f);
    *(float4*)&op[j] = o4;
  }
}

// --- layer-1 pre-projection: Z = X @ Wl1 (128 -> 64), no bias ---------------
struct ZArgs {
  const float* src[2];
  const unsigned short *Bh[2], *Bm[2];
  float* out[2];
};
__global__ __launch_bounds__(256, 5) void zproj(ZArgs a) {
  __shared__ __align__(16) unsigned short Ab[2 * kM * kH];  // 16 KB
  const int tid = threadIdx.x, dir = blockIdx.y;
  const size_t row0 = (size_t)blockIdx.x * kM;
  const float* __restrict__ src = a.src[dir];
  const unsigned short* __restrict__ Bh = a.Bh[dir];
  const unsigned short* __restrict__ Bm = a.Bm[dir];
  const int lane = tid & 63, w = tid >> 6, q = lane >> 4, ln = lane & 15;

  // issue staging + ALL weight loads, fence, then convert
  float4 va[4];
#pragma unroll
  for (int k = 0; k < 4; ++k) {
    const int c = tid + k * 256, r = c >> 5, j = c & 31;
    va[k] = *(const float4*)&src[(row0 + r) * kH + j * 4];
  }
  bf16x8 Bh4[4], Bm4[4];
#pragma unroll
  for (int kc = 0; kc < 4; ++kc) {
    const int off = (w * 16 + ln) * kH + kc * 32 + q * 8;
    Bh4[kc] = ldb8(&Bh[off]);
    Bm4[kc] = ldb8(&Bm[off]);
  }
  __builtin_amdgcn_sched_barrier(0);
#pragma unroll
  for (int k = 0; k < 4; ++k) {
    const int c = tid + k * 256, r = c >> 5, j = c & 31;
    const float* vv = &va[k].x;
    ushort4v h4, m4;
#pragma unroll
    for (int u = 0; u < 4; ++u) {
      unsigned short th, tm;
      split2(vv[u], th, tm);
      h4[u] = th; m4[u] = tm;
    }
    *(ushort4v*)ab_ptr(Ab, 0, r, j * 8) = h4;
    *(ushort4v*)ab_ptr(Ab, 1, r, j * 8) = m4;
  }
  floatx4 acc[2] = {}, accL[2] = {};
  __syncthreads();
#pragma unroll
  for (int kc = 0; kc < 4; ++kc) {
#pragma unroll
    for (int mt = 0; mt < 2; ++mt) {
      const int ro = mt * 16 + ln, cob = kc * 64 + q * 16;
      const bf16x8 ah = ldb8(ab_ptr(Ab, 0, ro, cob));
      const bf16x8 am = ldb8(ab_ptr(Ab, 1, ro, cob));
      acc[mt] = mfma16(ah, Bh4[kc], acc[mt]);
      floatx4 cl = accL[mt];
      cl = mfma16(ah, Bm4[kc], cl);
      cl = mfma16(am, Bh4[kc], cl);
      accL[mt] = cl;
    }
  }
  float* __restrict__ out = a.out[dir];
  const int col = w * 16 + ln;
#pragma unroll
  for (int mt = 0; mt < 2; ++mt)
#pragma unroll
    for (int r = 0; r < 4; ++r)
      out[(row0 + mt * 16 + q * 4 + r) * kOUT + col] =
          acc[mt][r] + accL[mt][r];
}

// --- layer-1 SAGE finish: D = root @ Wr1 + bl + aggz; LN (no ReLU) ----------
struct S1Args {
  const float* root[2];
  const float* aggz[2];
  const unsigned short *Bh[2], *Bm[2];
  const float *bl[2], *g[2], *b[2];
  float* out[2];
};
__global__ __launch_bounds__(256, 5) void sage1(S1Args a) {
  constexpr int NOUT = kOUT;
  __shared__ __align__(16) unsigned short Ab[2 * kM * kH];  // 16 KB
  float* Cs = (float*)Ab;  // reused post-MFMA: [kM][NOUT+1]
  const int tid = threadIdx.x, dir = blockIdx.y;
  const size_t row0 = (size_t)blockIdx.x * kM;
  const float* __restrict__ root = a.root[dir];
  const unsigned short* __restrict__ Bh = a.Bh[dir];
  const unsigned short* __restrict__ Bm = a.Bm[dir];
  const int lane = tid & 63, w = tid >> 6, q = lane >> 4, ln = lane & 15;

  float4 va[4];
#pragma unroll
  for (int k = 0; k < 4; ++k) {
    const int c = tid + k * 256, r = c >> 5, j = c & 31;
    va[k] = *(const float4*)&root[(row0 + r) * kH + j * 4];
  }
  bf16x8 Bh4[4], Bm4[4];
#pragma unroll
  for (int kc = 0; kc < 4; ++kc) {
    const int off = (w * 16 + ln) * kH + kc * 32 + q * 8;
    Bh4[kc] = ldb8(&Bh[off]);
    Bm4[kc] = ldb8(&Bm[off]);
  }
  __builtin_amdgcn_sched_barrier(0);
#pragma unroll
  for (int k = 0; k < 4; ++k) {
    const int c = tid + k * 256, r = c >> 5, j = c & 31;
    const float* vv = &va[k].x;
    ushort4v h4, m4;
#pragma unroll
    for (int u = 0; u < 4; ++u) {
      unsigned short th, tm;
      split2(vv[u], th, tm);
      h4[u] = th; m4[u] = tm;
    }
    *(ushort4v*)ab_ptr(Ab, 0, r, j * 8) = h4;
    *(ushort4v*)ab_ptr(Ab, 1, r, j * 8) = m4;
  }
  floatx4 acc[2] = {}, accL[2] = {};
  __syncthreads();
#pragma unroll
  for (int kc = 0; kc < 4; ++kc) {
#pragma unroll
    for (int mt = 0; mt < 2; ++mt) {
      const int ro = mt * 16 + ln, cob = kc * 64 + q * 16;
      const bf16x8 ah = ldb8(ab_ptr(Ab, 0, ro, cob));
      const bf16x8 am = ldb8(ab_ptr(Ab, 1, ro, cob));
      acc[mt] = mfma16(ah, Bh4[kc], acc[mt]);
      floatx4 cl = accL[mt];
      cl = mfma16(ah, Bm4[kc], cl);
      cl = mfma16(am, Bh4[kc], cl);
      accL[mt] = cl;
    }
  }
  __syncthreads();  // done reading Ab
  const float* __restrict__ blv = a.bl[dir];
  {
    const int col = w * 16 + ln;
    const float bv = blv[col];
#pragma unroll
    for (int mt = 0; mt < 2; ++mt)
#pragma unroll
      for (int r = 0; r < 4; ++r)
        Cs[(mt * 16 + q * 4 + r) * (NOUT + 1) + col] =
            (acc[mt][r] + accL[mt][r]) + bv;
  }
  __syncthreads();
  // LN over 64 cols: 8 threads/row, 8 cols each; add gathered term from global
  const int r = tid >> 3, sub = tid & 7;
  const float* __restrict__ az = a.aggz[dir];
  const float* __restrict__ gg = a.g[dir];
  const float* __restrict__ bb = a.b[dir];
  const float4 az0 = *(const float4*)&az[(row0 + r) * NOUT + sub * 8];
  const float4 az1 = *(const float4*)&az[(row0 + r) * NOUT + sub * 8 + 4];
  float vals[8], s = 0.f;
#pragma unroll
  for (int j = 0; j < 8; ++j) {
    const float v = Cs[r * (NOUT + 1) + sub * 8 + j] +
                    (j < 4 ? (&az0.x)[j] : (&az1.x)[j - 4]);
    vals[j] = v;
    s += v;
  }
#pragma unroll
  for (int o = 1; o < 8; o <<= 1) s += __shfl_xor(s, o, 64);
  const float mean = s * (1.0f / NOUT);
  float s2 = 0.f;
#pragma unroll
  for (int j = 0; j < 8; ++j) {
    const float d = vals[j] - mean;
    s2 += d * d;
  }
#pragma unroll
  for (int o = 1; o < 8; o <<= 1) s2 += __shfl_xor(s2, o, 64);
  const float rstd = rsqrtf(s2 * (1.0f / NOUT) + kEPS);
  float* op = a.out[dir] + (row0 + r) * NOUT + sub * 8;
#pragma unroll
  for (int j = 0; j < 8; j += 4) {
    float4 o4;
    float* oo = &o4.x;
#pragma unroll
    for (int jj = 0; jj < 4; ++jj)
      oo[jj] = (vals[j + jj] - mean) * rstd * gg[sub * 8 + j + jj] +
               bb[sub * 8 + j + jj];
    *(float4*)&op[j] = o4;
  }
}

extern "C" void kernel_launch(void* const* d_in, const int* in_sizes, int n_in,
                              void* d_out, int out_size, void* d_ws, size_t ws_size,
                              hipStream_t stream) {
  (void)in_sizes; (void)n_in; (void)out_size; (void)ws_size;
  const float* x_u    = (const float*)d_in[0];
  const float* x_i    = (const float*)d_in[1];
  const int*   e_ui   = (const int*)d_in[2];
  const int*   e_iu   = (const int*)d_in[3];
  const float* Wp_u   = (const float*)d_in[4];
  const float* bp_u   = (const float*)d_in[5];
  const float* Wp_i   = (const float*)d_in[6];
  const float* bp_i   = (const float*)d_in[7];
  const float* Wl0_ui = (const float*)d_in[8];
  const float* bl0_ui = (const float*)d_in[9];
  const float* Wr0_ui = (const float*)d_in[10];
  const float* Wl0_iu = (const float*)d_in[11];
  const float* bl0_iu = (const float*)d_in[12];
  const float* Wr0_iu = (const float*)d_in[13];
  const float* g0_u   = (const float*)d_in[14];
  const float* b0_u   = (const float*)d_in[15];
  const float* g0_i   = (const float*)d_in[16];
  const float* b0_i   = (const float*)d_in[17];
  const float* Wl1_ui = (const float*)d_in[18];
  const float* bl1_ui = (const float*)d_in[19];
  const float* Wr1_ui = (const float*)d_in[20];
  const float* Wl1_iu = (const float*)d_in[21];
  const float* bl1_iu = (const float*)d_in[22];
  const float* Wr1_iu = (const float*)d_in[23];
  const float* g1_u   = (const float*)d_in[24];
  const float* b1_u   = (const float*)d_in[25];
  const float* g1_i   = (const float*)d_in[26];
  const float* b1_i   = (const float*)d_in[27];

  // ---- workspace layout ----
  float* pf = (float*)d_ws;
  const size_t NH = (size_t)kNU * kH;  // 12.8M floats
  float* hu0 = pf;           // projected user feats (later: Zu | Zi)
  float* hi0 = pf + NH;      // projected item feats (later: aggzI | aggzU)
  float* b2  = pf + 2 * NH;  // aggI -> h_i1 (in-place)
  float* b3  = pf + 3 * NH;  // aggU -> h_u1 (in-place)
  float* Zu = hu0;
  float* Zi = hu0 + (size_t)kNU * kOUT;
  float* aggzI = hi0;
  float* aggzU = hi0 + (size_t)kNU * kOUT;
  unsigned short* wh = (unsigned short*)(pf + 4 * NH);  // 131072 ushorts each
  unsigned short* wm = wh + 131072;
  unsigned short* wl = wm + 131072;
  int* pi = (int*)(wl + 131072);
  int* cnt_u = pi; pi += kNU;
  int* cnt_i = pi; pi += kNU;
  int* ptr_u = pi; pi += kNU;
  int* ptr_i = pi; pi += kNU;
  int* cur_u = pi; pi += kNU;
  int* cur_i = pi; pi += kNU;
  int* tot   = pi; pi += 2 * 128;
  int* col_ui = pi; pi += kE;
  int* col_iu = pi; pi += kE;

  // weight sub-offsets (identical layout in h/m/l sets)
  const int oPu = 0, oPi = 12288, o0Lui = 32768, o0Rui = 49152,
            o0Liu = 65536, o0Riu = 81920, o1Lui = 98304, o1Rui = 106496,
            o1Liu = 114688, o1Riu = 122880;

  float* out_u = (float*)d_out;               // h_u2: [100000][64]
  float* out_i = out_u + (size_t)kNU * kOUT;  // h_i2: [100000][64]

  // ---- weight convert/transpose/3-split ----
  WcvtArgs wa;
  const float* wsrc[10] = {Wp_u, Wp_i, Wl0_ui, Wr0_ui, Wl0_iu, Wr0_iu,
                           Wl1_ui, Wr1_ui, Wl1_iu, Wr1_iu};
  const int woff[10] = {oPu, oPi, o0Lui, o0Rui, o0Liu, o0Riu,
                        o1Lui, o1Rui, o1Liu, o1Riu};
  const int wK[10] = {kFU, kFI, kH, kH, kH, kH, kH, kH, kH, kH};
  const int wN[10] = {kH, kH, kH, kH, kH, kH, kOUT, kOUT, kOUT, kOUT};
  for (int i = 0; i < 10; ++i) {
    wa.src[i] = wsrc[i];
    wa.dh[i] = wh + woff[i];
    wa.dm[i] = wm + woff[i];
    wa.dl[i] = wl + woff[i];
    wa.K[i] = wK[i];
    wa.N[i] = wN[i];
  }
  wcvt<<<dim3(80, 10), 256, 0, stream>>>(wa);

  // ---- CSR build (XCD-partitioned) overlapped with projections ----
  zero_int<<<256, 256, 0, stream>>>(cnt_u, 2 * kNU);
  hist_proj<<<8 * kEB + kNBLK, 256, 0, stream>>>(e_ui, e_iu, cnt_i, cnt_u, x_u,
                                                 wh + oPu, wm + oPu, wl + oPu,
                                                 bp_u, hu0);
  scanA<<<dim3(kNCHUNK, 2), 1024, 0, stream>>>(cnt_u, cnt_i, ptr_u, ptr_i, tot);
  scanB<<<2, 128, 0, stream>>>(tot);
  scanC<<<dim3(kNCHUNK, 2), 1024, 0, stream>>>(ptr_u, ptr_i, tot, cur_u, cur_i);
  fill_proj<<<8 * kEB + kNBLK, 256, 0, stream>>>(e_ui, e_iu, cur_i, cur_u,
                                                 col_ui, col_iu, x_i, wh + oPi,
                                                 wm + oPi, wl + oPi, bp_i, hi0);

  // ---- layer 0: gather (both dirs) then SAGE (both dirs) ----
  AggArgs g0;
  g0.src[0] = hu0; g0.ptr[0] = ptr_i; g0.cur[0] = cur_i; g0.col[0] = col_ui;
  g0.out[0] = b2;
  g0.src[1] = hi0; g0.ptr[1] = ptr_u; g0.cur[1] = cur_u; g0.col[1] = col_iu;
  g0.out[1] = b3;
  agg2<kH><<<dim3(kNU / 4, 2), 256, 0, stream>>>(g0);

  FsArgs a0;
  a0.agg[0] = b2; a0.root[0] = hi0;
  a0.WLh[0] = wh + o0Lui; a0.WLm[0] = wm + o0Lui;
  a0.WRh[0] = wh + o0Rui; a0.WRm[0] = wm + o0Rui;
  a0.bl[0] = bl0_ui; a0.g[0] = g0_i; a0.b[0] = b0_i; a0.out[0] = b2;  // h_i1
  a0.agg[1] = b3; a0.root[1] = hu0;
  a0.WLh[1] = wh + o0Liu; a0.WLm[1] = wm + o0Liu;
  a0.WRh[1] = wh + o0Riu; a0.WRm[1] = wm + o0Riu;
  a0.bl[1] = bl0_iu; a0.g[1] = g0_u; a0.b[1] = b0_u; a0.out[1] = b3;  // h_u1
  sage0<<<dim3(kNBLK, 2), 256, 0, stream>>>(a0);

  // ---- layer 1: pre-project Z = h1 @ Wl1 (64-wide), gather Z, finish ----
  ZArgs zp;
  zp.src[0] = b3;  // h_u1 -> Zu (for item aggregation)
  zp.Bh[0] = wh + o1Lui; zp.Bm[0] = wm + o1Lui;
  zp.out[0] = Zu;
  zp.src[1] = b2;  // h_i1 -> Zi (for user aggregation)
  zp.Bh[1] = wh + o1Liu; zp.Bm[1] = wm + o1Liu;
  zp.out[1] = Zi;
  zproj<<<dim3(kNBLK, 2), 256, 0, stream>>>(zp);

  AggArgs g1;
  g1.src[0] = Zu; g1.ptr[0] = ptr_i; g1.cur[0] = cur_i; g1.col[0] = col_ui;
  g1.out[0] = aggzI;
  g1.src[1] = Zi; g1.ptr[1] = ptr_u; g1.cur[1] = cur_u; g1.col[1] = col_iu;
  g1.out[1] = aggzU;
  agg2<kOUT><<<dim3(kNU / 4, 2), 256, 0, stream>>>(g1);

  S1Args s1;
  s1.root[0] = b2; s1.aggz[0] = aggzI;
  s1.Bh[0] = wh + o1Rui; s1.Bm[0] = wm + o1Rui;
  s1.bl[0] = bl1_ui; s1.g[0] = g1_i; s1.b[0] = b1_i; s1.out[0] = out_i;
  s1.root[1] = b3; s1.aggz[1] = aggzU;
  s1.Bh[1] = wh + o1Riu; s1.Bm[1] = wm + o1Riu;
  s1.bl[1] = bl1_iu; s1.g[1] = g1_u; s1.b[1] = b1_u; s1.out[1] = out_u;
  sage1<<<dim3(kNBLK, 2), 256, 0, stream>>>(s1);
}